// Round 3
// baseline (694.429 us; speedup 1.0000x reference)
//
#include <hip/hip_runtime.h>
#include <hip/hip_bf16.h>
#include <math.h>

#define NN 50000
#define EE 800000
#define GG 256
#define NCH 4
#define CHDIV 12500
#define N2 (NN * NCH)
#define NV 13

typedef short bf16x8 __attribute__((ext_vector_type(8)));
typedef float f32x4 __attribute__((ext_vector_type(4)));

__device__ __forceinline__ unsigned short f2bf(float x) {
    __hip_bfloat16 h = __float2bfloat16(x);
    union { __hip_bfloat16 h; unsigned short u; } c; c.h = h; return c.u;
}
__device__ __forceinline__ float bf2f(unsigned short u) {
    union { unsigned int v; float f; } t; t.v = ((unsigned int)u) << 16; return t.f;
}
__device__ __forceinline__ float gelu_f(float v) {
    return 0.5f * v * (1.0f + erff(v * 0.70710678118654752f));
}
// XOR swizzle for [rows][128 bf16] LDS tiles (256B row stride)
__device__ __forceinline__ int swz(int row, int bytecol) {
    return row * 256 + (bytecol ^ ((row & 7) << 4));
}

// ---------------- graph prep ----------------
// counts per (dst, src-chunk) sub-row
__global__ void k_deg(const int* __restrict__ src, const int* __restrict__ dst,
                      int* __restrict__ deg2, int E) {
    int i = blockIdx.x * blockDim.x + threadIdx.x;
    if (i < E) {
        int c = src[i] / CHDIV;
        atomicAdd(&deg2[dst[i] * NCH + c], 1);
    }
}
__global__ void k_dis(const int* __restrict__ deg2, float* __restrict__ dis, int N) {
    int i = blockIdx.x * blockDim.x + threadIdx.x;
    if (i < N) {
        const int4 dd = *(const int4*)(deg2 + i * 4);
        dis[i] = rsqrtf((float)(dd.x + dd.y + dd.z + dd.w + 1)); // +1 self loop
    }
}
__global__ void k_scan1(const int* __restrict__ deg2, int* __restrict__ incl,
                        int* __restrict__ bsum, int N) {
    __shared__ int sm[1024];
    int t = threadIdx.x, i = blockIdx.x * 1024 + t;
    int v = (i < N) ? deg2[i] : 0;
    sm[t] = v;
    __syncthreads();
    for (int off = 1; off < 1024; off <<= 1) {
        int add = (t >= off) ? sm[t - off] : 0;
        __syncthreads();
        sm[t] += add;
        __syncthreads();
    }
    if (i < N) incl[i] = sm[t];
    if (t == 1023) bsum[blockIdx.x] = sm[t];
}
__global__ void k_scan2(const int* __restrict__ bsum, int* __restrict__ boff, int nb) {
    if (threadIdx.x == 0 && blockIdx.x == 0) {
        int run = 0;
        for (int b = 0; b < nb; ++b) { boff[b] = run; run += bsum[b]; }
    }
}
__global__ void k_scan3(const int* __restrict__ incl, const int* __restrict__ deg2,
                        const int* __restrict__ boff, int* __restrict__ rowstart2, int N, int E) {
    int i = blockIdx.x * blockDim.x + threadIdx.x;
    if (i < N) rowstart2[i] = incl[i] - deg2[i] + boff[i >> 10];
    if (i == 0) rowstart2[N] = E;
}
__global__ void k_fill(const int* __restrict__ src, const int* __restrict__ dst,
                       const float* __restrict__ dis, const int* __restrict__ rowstart2,
                       int* __restrict__ fillc2, int* __restrict__ col,
                       float* __restrict__ wn, int E) {
    int i = blockIdx.x * blockDim.x + threadIdx.x;
    if (i < E) {
        int s = src[i], d = dst[i];
        int idx = d * NCH + s / CHDIV;
        int pos = rowstart2[idx] + atomicAdd(&fillc2[idx], 1);
        col[pos] = s;
        wn[pos] = dis[s] * dis[d];
    }
}
// all 8 weight matrices fp32 [k][n] -> bf16 transposed+preswizzled, one launch
__global__ void k_prepw8(const float* __restrict__ w0, const float* __restrict__ w1,
                         const float* __restrict__ w2, const float* __restrict__ w3,
                         const float* __restrict__ w4, const float* __restrict__ w5,
                         const float* __restrict__ w6, const float* __restrict__ w7,
                         unsigned short* __restrict__ Wt) {
    int b = blockIdx.x >> 6;
    const float* W = b == 0 ? w0 : b == 1 ? w1 : b == 2 ? w2 : b == 3 ? w3
                   : b == 4 ? w4 : b == 5 ? w5 : b == 6 ? w6 : w7;
    int tid = (blockIdx.x & 63) * 256 + threadIdx.x; // 0..16383
    int n = tid >> 7, k = tid & 127;
    *(unsigned short*)((char*)(Wt + (size_t)b * 16384) + swz(n, k * 2)) = f2bf(W[k * 128 + n]);
}
__global__ void k_gbounds(const int* __restrict__ batch, int* __restrict__ gstart, int N, int G) {
    int g = blockIdx.x * blockDim.x + threadIdx.x;
    if (g > G) return;
    int lo = 0, hi = N;
    while (lo < hi) { int mid = (lo + hi) >> 1; if (batch[mid] < g) lo = mid + 1; else hi = mid; }
    gstart[g] = lo;
}

// ---------------- fused GEMM: out = epi(A' @ W + b) ---------------- (unchanged)
__global__ __launch_bounds__(256) void k_gemm(
    const float* __restrict__ A32, const unsigned short* __restrict__ A16,
    const unsigned short* __restrict__ Wt, const float* __restrict__ bias,
    const float* __restrict__ lscale, const float* __restrict__ lshift,
    int gelu,
    const float* __restrict__ res32, const float* __restrict__ rscale, const float* __restrict__ rshift,
    float* __restrict__ out32, unsigned short* __restrict__ out16, int M)
{
    __shared__ unsigned short As[64 * 128];
    __shared__ unsigned short Ws[128 * 128];
    const int tid = threadIdx.x;
    const int bm = blockIdx.x * 64;
    {
        const uint4* srcp = (const uint4*)Wt;
        uint4* dstp = (uint4*)Ws;
        for (int i = tid; i < (128 * 128) / 8; i += 256) dstp[i] = srcp[i];
    }
    #pragma unroll
    for (int pass = 0; pass < 4; ++pass) {
        int row = pass * 16 + (tid >> 4);
        int c8 = tid & 15;
        int gr = bm + row; if (gr > M - 1) gr = M - 1;
        unsigned short tmp[8];
        if (A32) {
            const float* pp = A32 + (size_t)gr * 128 + c8 * 8;
            float4 v0 = *(const float4*)pp;
            float4 v1 = *(const float4*)(pp + 4);
            float vv[8] = { v0.x, v0.y, v0.z, v0.w, v1.x, v1.y, v1.z, v1.w };
            if (lscale) {
                int ch = c8 * 8;
                #pragma unroll
                for (int j = 0; j < 8; ++j) vv[j] = vv[j] * lscale[ch + j] + lshift[ch + j];
            }
            #pragma unroll
            for (int j = 0; j < 8; ++j) tmp[j] = f2bf(vv[j]);
        } else {
            *(uint4*)tmp = *(const uint4*)(A16 + (size_t)gr * 128 + c8 * 8);
        }
        *(uint4*)((char*)As + swz(row, c8 * 16)) = *(uint4*)tmp;
    }
    __syncthreads();

    const int lane = tid & 63, wid = tid >> 6;
    const int r0 = wid * 16;
    const int lrow = lane & 15;
    const int lkb = (lane >> 4) * 16;
    f32x4 acc[8];
    #pragma unroll
    for (int n = 0; n < 8; ++n) acc[n] = (f32x4){0.f, 0.f, 0.f, 0.f};
    #pragma unroll
    for (int kk = 0; kk < 4; ++kk) {
        int bc = kk * 64 + lkb;
        bf16x8 a = *(const bf16x8*)((const char*)As + swz(r0 + lrow, bc));
        #pragma unroll
        for (int n = 0; n < 8; ++n) {
            bf16x8 b = *(const bf16x8*)((const char*)Ws + swz(n * 16 + lrow, bc));
            acc[n] = __builtin_amdgcn_mfma_f32_16x16x32_bf16(a, b, acc[n], 0, 0, 0);
        }
    }
    const int cb = lane & 15;
    const int rb = r0 + (lane >> 4) * 4;
    #pragma unroll
    for (int n = 0; n < 8; ++n) {
        int colg = n * 16 + cb;
        float bv = bias ? bias[colg] : 0.f;
        #pragma unroll
        for (int j = 0; j < 4; ++j) {
            int rowg = bm + rb + j;
            if (rowg < M) {
                float v = acc[n][j] + bv;
                if (gelu) v = gelu_f(v);
                if (res32) {
                    float r = res32[(size_t)rowg * 128 + colg];
                    if (rscale) r = r * rscale[colg] + rshift[colg];
                    v += r;
                }
                if (out32) out32[(size_t)rowg * 128 + colg] = v;
                if (out16) out16[(size_t)rowg * 128 + colg] = f2bf(v);
            }
        }
    }
}

// ---------------- chunked CSR aggregation + residual + BN stats ----------------
// Wave owns NV consecutive nodes; fp32 accumulators in registers; sweeps the 4
// src-chunks in globally-aligned order so concurrent gathers stay in one 3.2MB
// L2-resident slice of xw. 4 groups x 16 lanes x 16B per edge row.
__global__ __launch_bounds__(256) void k_agg(
    const unsigned short* __restrict__ xw, const int* __restrict__ rowstart2,
    const int* __restrict__ col, const float* __restrict__ wn,
    const float* __restrict__ dis, const float* __restrict__ convb,
    const float* __restrict__ x0, float* __restrict__ z,
    float* __restrict__ bnsum, float* __restrict__ bnsq, int N)
{
    __shared__ float redS[4][128];
    __shared__ float redQ[4][128];
    const int tid = threadIdx.x;
    const int lane = tid & 63;
    const int wid = tid >> 6;
    const int g = lane >> 4;        // edge sub-group 0..3
    const int cl = lane & 15;       // channel lane 0..15
    const int ch = cl * 8;          // owns 8 channels
    const int wave = blockIdx.x * 4 + wid;
    const int v0 = wave * NV;

    float a[NV][8];
    #pragma unroll
    for (int nv = 0; nv < NV; ++nv)
        #pragma unroll
        for (int j = 0; j < 8; ++j) a[nv][j] = 0.f;

    for (int c = 0; c < NCH; ++c) {
        #pragma unroll
        for (int nv = 0; nv < NV; ++nv) {
            const int v = v0 + nv;
            if (v < N) {
                const int r = (v << 2) | c;
                const int e1 = rowstart2[r + 1];
                for (int e = rowstart2[r] + g; e < e1; e += 4) {
                    const int u = col[e];
                    const float w = wn[e];
                    uint4 p = *(const uint4*)(xw + (size_t)u * 128 + ch);
                    const unsigned int pw[4] = { p.x, p.y, p.z, p.w };
                    #pragma unroll
                    for (int d = 0; d < 4; ++d) {
                        a[nv][2 * d]     += w * bf2f((unsigned short)(pw[d] & 0xffff));
                        a[nv][2 * d + 1] += w * bf2f((unsigned short)(pw[d] >> 16));
                    }
                }
            }
        }
    }

    float s[8], q[8];
    #pragma unroll
    for (int j = 0; j < 8; ++j) { s[j] = 0.f; q[j] = 0.f; }
    float cb[8];
    #pragma unroll
    for (int j = 0; j < 8; ++j) cb[j] = convb[ch + j];

    #pragma unroll
    for (int nv = 0; nv < NV; ++nv) {
        const int v = v0 + nv;
        if (v >= N) break; // wave-uniform
        float t[8];
        #pragma unroll
        for (int j = 0; j < 8; ++j) {
            float x = a[nv][j];
            x += __shfl_xor(x, 16, 64);
            x += __shfl_xor(x, 32, 64);
            t[j] = x;
        }
        if (g == 0) {
            const float dv = dis[v];
            const float sw = dv * dv; // self-loop norm
            uint4 p = *(const uint4*)(xw + (size_t)v * 128 + ch);
            const unsigned int pw[4] = { p.x, p.y, p.z, p.w };
            float4 xa = *(const float4*)(x0 + (size_t)v * 128 + ch);
            float4 xb = *(const float4*)(x0 + (size_t)v * 128 + ch + 4);
            const float xr[8] = { xa.x, xa.y, xa.z, xa.w, xb.x, xb.y, xb.z, xb.w };
            float zz[8];
            #pragma unroll
            for (int d = 0; d < 4; ++d) {
                zz[2 * d]     = t[2 * d]     + sw * bf2f((unsigned short)(pw[d] & 0xffff));
                zz[2 * d + 1] = t[2 * d + 1] + sw * bf2f((unsigned short)(pw[d] >> 16));
            }
            #pragma unroll
            for (int j = 0; j < 8; ++j) {
                zz[j] += cb[j] + xr[j];
                s[j] += zz[j];
                q[j] += zz[j] * zz[j];
            }
            *(float4*)(z + (size_t)v * 128 + ch)     = make_float4(zz[0], zz[1], zz[2], zz[3]);
            *(float4*)(z + (size_t)v * 128 + ch + 4) = make_float4(zz[4], zz[5], zz[6], zz[7]);
        }
    }
    if (g == 0) {
        #pragma unroll
        for (int j = 0; j < 8; ++j) { redS[wid][ch + j] = s[j]; redQ[wid][ch + j] = q[j]; }
    }
    __syncthreads();
    if (tid < 128) {
        float ts = redS[0][tid] + redS[1][tid] + redS[2][tid] + redS[3][tid];
        float tq = redQ[0][tid] + redQ[1][tid] + redQ[2][tid] + redQ[3][tid];
        atomicAdd(&bnsum[tid], ts);
        atomicAdd(&bnsq[tid], tq);
    }
}
__global__ void k_bnfin(float* __restrict__ bnsum, float* __restrict__ bnsq,
                        const float* __restrict__ gamma, const float* __restrict__ beta,
                        float* __restrict__ scale, float* __restrict__ shift, float invN) {
    int c = threadIdx.x;
    float m = bnsum[c] * invN;
    float var = bnsq[c] * invN - m * m;
    float s = gamma[c] * rsqrtf(var + 1e-5f);
    scale[c] = s;
    shift[c] = beta[c] - m * s;
    bnsum[c] = 0.f;  // re-zero for next hop
    bnsq[c] = 0.f;
}
// fused global_mean_pool + post FFNN (exact fp32)
__global__ __launch_bounds__(128) void k_poolpost(
    const float* __restrict__ x, const int* __restrict__ gstart,
    const float* __restrict__ w1, const float* __restrict__ b1,
    const float* __restrict__ w2, const float* __restrict__ b2,
    float* __restrict__ out, int G)
{
    __shared__ float pr[128], hr[128];
    int g = blockIdx.x, t = threadIdx.x;
    int s = gstart[g], e = gstart[g + 1];
    float acc = 0;
    for (int v = s; v < e; ++v) acc += x[(size_t)v * 128 + t];
    pr[t] = acc / fmaxf((float)(e - s), 1.0f);
    __syncthreads();
    float a = b1[t];
    for (int k = 0; k < 128; ++k) a += pr[k] * w1[k * 128 + t];
    hr[t] = gelu_f(a);
    __syncthreads();
    if (t < 64) {
        float o = b2[t];
        for (int k = 0; k < 128; ++k) o += hr[k] * w2[k * 64 + t];
        out[g * 64 + t] = o;
    }
}

extern "C" void kernel_launch(void* const* d_in, const int* in_sizes, int n_in,
                              void* d_out, int out_size, void* d_ws, size_t ws_size,
                              hipStream_t stream) {
    (void)in_sizes; (void)n_in; (void)out_size; (void)ws_size;
    const float* x_in    = (const float*)d_in[0];
    const int*   ei      = (const int*)d_in[1];
    const int*   batch   = (const int*)d_in[2];
    const float* pre_w1  = (const float*)d_in[3];
    const float* pre_b1  = (const float*)d_in[4];
    const float* pre_w2  = (const float*)d_in[5];
    const float* pre_b2  = (const float*)d_in[6];
    const float* conv_w  = (const float*)d_in[7];
    const float* conv_b  = (const float*)d_in[8];
    const float* ffnn_w1 = (const float*)d_in[9];
    const float* ffnn_b1 = (const float*)d_in[10];
    const float* ffnn_w2 = (const float*)d_in[11];
    const float* ffnn_b2 = (const float*)d_in[12];
    const float* bn_gamma= (const float*)d_in[13];
    const float* bn_beta = (const float*)d_in[14];
    const float* post_w1 = (const float*)d_in[15];
    const float* post_b1 = (const float*)d_in[16];
    const float* post_w2 = (const float*)d_in[17];
    const float* post_b2 = (const float*)d_in[18];
    const int* srcE = ei;
    const int* dstE = ei + EE;

    char* base = (char*)d_ws;
    size_t off = 0;
    auto carve = [&](size_t bytes) {
        char* q = base + off;
        off = (off + bytes + 255) & ~(size_t)255;
        return q;
    };
    float* xf32 = (float*)carve((size_t)NN * 128 * 4);
    float* zf32 = (float*)carve((size_t)NN * 128 * 4);
    unsigned short* xbf = (unsigned short*)carve((size_t)NN * 128 * 2);
    unsigned short* hbf = (unsigned short*)carve((size_t)NN * 128 * 2);
    float* dis   = (float*)carve((size_t)NN * 4);
    int* deg2    = (int*)carve((size_t)N2 * 4);
    int* fillc2  = (int*)carve((size_t)N2 * 4);
    int* incl    = (int*)carve((size_t)N2 * 4);
    int* bsum    = (int*)carve(256 * 4);
    int* boff    = (int*)carve(256 * 4);
    int* rowstart2 = (int*)carve((size_t)(N2 + 1) * 4);
    int* colx    = (int*)carve((size_t)EE * 4);
    float* wn    = (float*)carve((size_t)EE * 4);
    unsigned short* Wt = (unsigned short*)carve((size_t)8 * 16384 * 2);
    float* bnsumb  = (float*)carve(128 * 4);
    float* bnsqb   = (float*)carve(128 * 4);
    float* bnscale = (float*)carve(128 * 4);
    float* bnshift = (float*)carve(128 * 4);
    int* gstart    = (int*)carve((size_t)(GG + 1) * 4);

    hipMemsetAsync(deg2, 0, (size_t)N2 * 4, stream);
    hipMemsetAsync(fillc2, 0, (size_t)N2 * 4, stream);
    hipMemsetAsync(bnsumb, 0, 128 * 4, stream);
    hipMemsetAsync(bnsqb, 0, 128 * 4, stream);

    k_deg<<<(EE + 255) / 256, 256, 0, stream>>>(srcE, dstE, deg2, EE);
    k_dis<<<(NN + 255) / 256, 256, 0, stream>>>(deg2, dis, NN);
    const int nsb = (N2 + 1023) / 1024;
    k_scan1<<<nsb, 1024, 0, stream>>>(deg2, incl, bsum, N2);
    k_scan2<<<1, 1, 0, stream>>>(bsum, boff, nsb);
    k_scan3<<<(N2 + 255) / 256, 256, 0, stream>>>(incl, deg2, boff, rowstart2, N2, EE);
    k_fill<<<(EE + 255) / 256, 256, 0, stream>>>(srcE, dstE, dis, rowstart2, fillc2, colx, wn, EE);

    k_prepw8<<<512, 256, 0, stream>>>(pre_w1, pre_w2, conv_w, conv_w + 16384,
                                      ffnn_w1, ffnn_w1 + 16384, ffnn_w2, ffnn_w2 + 16384, Wt);
    k_gbounds<<<2, 256, 0, stream>>>(batch, gstart, NN, GG);

    const int gB = (NN + 63) / 64;
    const int aggB = ((NN + NV - 1) / NV + 3) / 4;
    k_gemm<<<gB, 256, 0, stream>>>(x_in, nullptr, Wt + 0 * 16384, pre_b1, nullptr, nullptr, 1,
                                   nullptr, nullptr, nullptr, nullptr, hbf, NN);
    k_gemm<<<gB, 256, 0, stream>>>(nullptr, hbf, Wt + 1 * 16384, pre_b2, nullptr, nullptr, 0,
                                   nullptr, nullptr, nullptr, xf32, xbf, NN);
    for (int i = 0; i < 2; ++i) {
        k_gemm<<<gB, 256, 0, stream>>>(nullptr, xbf, Wt + (2 + i) * 16384, nullptr, nullptr, nullptr, 0,
                                       nullptr, nullptr, nullptr, nullptr, hbf, NN);
        k_agg<<<aggB, 256, 0, stream>>>(hbf, rowstart2, colx, wn, dis, conv_b + i * 128,
                                        xf32, zf32, bnsumb, bnsqb, NN);
        k_bnfin<<<1, 128, 0, stream>>>(bnsumb, bnsqb, bn_gamma + i * 128, bn_beta + i * 128,
                                       bnscale, bnshift, 1.0f / NN);
        k_gemm<<<gB, 256, 0, stream>>>(zf32, nullptr, Wt + (4 + i) * 16384, ffnn_b1 + i * 128, bnscale, bnshift, 1,
                                       nullptr, nullptr, nullptr, nullptr, hbf, NN);
        k_gemm<<<gB, 256, 0, stream>>>(nullptr, hbf, Wt + (6 + i) * 16384, ffnn_b2 + i * 128, nullptr, nullptr, 0,
                                       zf32, bnscale, bnshift, xf32, xbf, NN);
    }
    k_poolpost<<<GG, 128, 0, stream>>>(xf32, gstart, post_w1, post_b1, post_w2, post_b2,
                                       (float*)d_out, GG);
}

// Round 4
// 567.605 us; speedup vs baseline: 1.2234x; 1.2234x over previous
//
#include <hip/hip_runtime.h>
#include <hip/hip_bf16.h>
#include <math.h>

#define NN 50000
#define EE 800000
#define GG 256

typedef short bf16x8 __attribute__((ext_vector_type(8)));
typedef float f32x4 __attribute__((ext_vector_type(4)));

__device__ __forceinline__ unsigned short f2bf(float x) {
    __hip_bfloat16 h = __float2bfloat16(x);
    union { __hip_bfloat16 h; unsigned short u; } c; c.h = h; return c.u;
}
__device__ __forceinline__ float bf2f(unsigned short u) {
    union { unsigned int v; float f; } t; t.v = ((unsigned int)u) << 16; return t.f;
}
__device__ __forceinline__ float gelu_f(float v) {
    return 0.5f * v * (1.0f + erff(v * 0.70710678118654752f));
}
// XOR swizzle for [rows][128 bf16] LDS tiles (256B row stride)
__device__ __forceinline__ int swz(int row, int bytecol) {
    return row * 256 + (bytecol ^ ((row & 7) << 4));
}

// ---------------- graph prep ----------------
__global__ void k_deg(const int* __restrict__ dst, int* __restrict__ degi, int E) {
    int i = blockIdx.x * blockDim.x + threadIdx.x;
    if (i < E) atomicAdd(&degi[dst[i]], 1);
}
__global__ void k_dis(const int* __restrict__ degi, float* __restrict__ dis, int N) {
    int i = blockIdx.x * blockDim.x + threadIdx.x;
    if (i < N) dis[i] = rsqrtf((float)(degi[i] + 1)); // +1 self loop
}
__global__ void k_scan1(const int* __restrict__ degi, int* __restrict__ incl,
                        int* __restrict__ bsum, int N) {
    __shared__ int sm[1024];
    int t = threadIdx.x, i = blockIdx.x * 1024 + t;
    int v = (i < N) ? degi[i] : 0;
    sm[t] = v;
    __syncthreads();
    for (int off = 1; off < 1024; off <<= 1) {
        int add = (t >= off) ? sm[t - off] : 0;
        __syncthreads();
        sm[t] += add;
        __syncthreads();
    }
    if (i < N) incl[i] = sm[t];
    if (t == 1023) bsum[blockIdx.x] = sm[t];
}
__global__ void k_scan2(const int* __restrict__ bsum, int* __restrict__ boff, int nb) {
    if (threadIdx.x == 0 && blockIdx.x == 0) {
        int run = 0;
        for (int b = 0; b < nb; ++b) { boff[b] = run; run += bsum[b]; }
    }
}
__global__ void k_scan3(const int* __restrict__ incl, const int* __restrict__ degi,
                        const int* __restrict__ boff, int* __restrict__ rowstart, int N, int E) {
    int i = blockIdx.x * blockDim.x + threadIdx.x;
    if (i < N) rowstart[i] = incl[i] - degi[i] + boff[i >> 10];
    if (i == 0) rowstart[N] = E;
}
__global__ void k_fill(const int* __restrict__ src, const int* __restrict__ dst,
                       const float* __restrict__ dis, const int* __restrict__ rowstart,
                       int* __restrict__ fillc, int* __restrict__ col,
                       float* __restrict__ wn, int E) {
    int i = blockIdx.x * blockDim.x + threadIdx.x;
    if (i < E) {
        int s = src[i], d = dst[i];
        int pos = rowstart[d] + atomicAdd(&fillc[d], 1);
        col[pos] = s;
        wn[pos] = dis[s] * dis[d];
    }
}
// all 8 weight matrices fp32 [k][n] -> bf16 transposed+preswizzled, one launch
__global__ void k_prepw8(const float* __restrict__ w0, const float* __restrict__ w1,
                         const float* __restrict__ w2, const float* __restrict__ w3,
                         const float* __restrict__ w4, const float* __restrict__ w5,
                         const float* __restrict__ w6, const float* __restrict__ w7,
                         unsigned short* __restrict__ Wt) {
    int b = blockIdx.x >> 6;
    const float* W = b == 0 ? w0 : b == 1 ? w1 : b == 2 ? w2 : b == 3 ? w3
                   : b == 4 ? w4 : b == 5 ? w5 : b == 6 ? w6 : w7;
    int tid = (blockIdx.x & 63) * 256 + threadIdx.x; // 0..16383
    int n = tid >> 7, k = tid & 127;
    *(unsigned short*)((char*)(Wt + (size_t)b * 16384) + swz(n, k * 2)) = f2bf(W[k * 128 + n]);
}
__global__ void k_gbounds(const int* __restrict__ batch, int* __restrict__ gstart, int N, int G) {
    int g = blockIdx.x * blockDim.x + threadIdx.x;
    if (g > G) return;
    int lo = 0, hi = N;
    while (lo < hi) { int mid = (lo + hi) >> 1; if (batch[mid] < g) lo = mid + 1; else hi = mid; }
    gstart[g] = lo;
}

// ---------------- fused GEMM: out = epi(A' @ W + b) ----------------
// Optional BN: stats (sum/sq + gamma/beta) -> scale/shift computed in LDS
// prologue; lbn applies affine to A on load, rbn applies it to the residual.
__global__ __launch_bounds__(256) void k_gemm(
    const float* __restrict__ A32, const unsigned short* __restrict__ A16,
    const unsigned short* __restrict__ Wt, const float* __restrict__ bias,
    const float* __restrict__ st_sum, const float* __restrict__ st_sq,
    const float* __restrict__ st_g, const float* __restrict__ st_b,
    float invN, int lbn, int gelu,
    const float* __restrict__ res32, int rbn,
    float* __restrict__ out32, unsigned short* __restrict__ out16, int M)
{
    __shared__ unsigned short As[64 * 128];
    __shared__ unsigned short Ws[128 * 128];
    __shared__ float lsc[128], lsh[128];
    const int tid = threadIdx.x;
    const int bm = blockIdx.x * 64;
    if (st_sum) {
        if (tid < 128) {
            float m = st_sum[tid] * invN;
            float var = st_sq[tid] * invN - m * m;
            float s = st_g[tid] * rsqrtf(var + 1e-5f);
            lsc[tid] = s;
            lsh[tid] = st_b[tid] - m * s;
        }
        __syncthreads();
    }
    {
        const uint4* srcp = (const uint4*)Wt;
        uint4* dstp = (uint4*)Ws;
        for (int i = tid; i < (128 * 128) / 8; i += 256) dstp[i] = srcp[i];
    }
    #pragma unroll
    for (int pass = 0; pass < 4; ++pass) {
        int row = pass * 16 + (tid >> 4);
        int c8 = tid & 15;
        int gr = bm + row; if (gr > M - 1) gr = M - 1;
        unsigned short tmp[8];
        if (A32) {
            const float* pp = A32 + (size_t)gr * 128 + c8 * 8;
            float4 v0 = *(const float4*)pp;
            float4 v1 = *(const float4*)(pp + 4);
            float vv[8] = { v0.x, v0.y, v0.z, v0.w, v1.x, v1.y, v1.z, v1.w };
            if (lbn) {
                int ch = c8 * 8;
                #pragma unroll
                for (int j = 0; j < 8; ++j) vv[j] = vv[j] * lsc[ch + j] + lsh[ch + j];
            }
            #pragma unroll
            for (int j = 0; j < 8; ++j) tmp[j] = f2bf(vv[j]);
        } else {
            *(uint4*)tmp = *(const uint4*)(A16 + (size_t)gr * 128 + c8 * 8);
        }
        *(uint4*)((char*)As + swz(row, c8 * 16)) = *(uint4*)tmp;
    }
    __syncthreads();

    const int lane = tid & 63, wid = tid >> 6;
    const int r0 = wid * 16;
    const int lrow = lane & 15;
    const int lkb = (lane >> 4) * 16;
    f32x4 acc[8];
    #pragma unroll
    for (int n = 0; n < 8; ++n) acc[n] = (f32x4){0.f, 0.f, 0.f, 0.f};
    #pragma unroll
    for (int kk = 0; kk < 4; ++kk) {
        int bc = kk * 64 + lkb;
        bf16x8 a = *(const bf16x8*)((const char*)As + swz(r0 + lrow, bc));
        #pragma unroll
        for (int n = 0; n < 8; ++n) {
            bf16x8 b = *(const bf16x8*)((const char*)Ws + swz(n * 16 + lrow, bc));
            acc[n] = __builtin_amdgcn_mfma_f32_16x16x32_bf16(a, b, acc[n], 0, 0, 0);
        }
    }
    const int cb = lane & 15;
    const int rb = r0 + (lane >> 4) * 4;
    #pragma unroll
    for (int n = 0; n < 8; ++n) {
        int colg = n * 16 + cb;
        float bv = bias ? bias[colg] : 0.f;
        #pragma unroll
        for (int j = 0; j < 4; ++j) {
            int rowg = bm + rb + j;
            if (rowg < M) {
                float v = acc[n][j] + bv;
                if (gelu) v = gelu_f(v);
                if (res32) {
                    float r = res32[(size_t)rowg * 128 + colg];
                    if (rbn) r = r * lsc[colg] + lsh[colg];
                    v += r;
                }
                if (out32) out32[(size_t)rowg * 128 + colg] = v;
                if (out16) out16[(size_t)rowg * 128 + colg] = f2bf(v);
            }
        }
    }
}

// ---------------- CSR aggregation + residual + BN partial stats ----------------
// Wave-per-node (grid-stride); 16-lane groups x 4; 2 edges (2x16B gathers) in
// flight per lane per iteration; butterfly reduce; g==0 finalizes + BN stats.
__global__ __launch_bounds__(256) void k_agg(
    const unsigned short* __restrict__ xw, const int* __restrict__ rowstart,
    const int* __restrict__ col, const float* __restrict__ wn,
    const float* __restrict__ dis, const float* __restrict__ convb,
    const float* __restrict__ x0, float* __restrict__ z,
    float* __restrict__ bnsum, float* __restrict__ bnsq, int N)
{
    __shared__ float redS[4][128];
    __shared__ float redQ[4][128];
    const int tid = threadIdx.x;
    const int lane = tid & 63;
    const int wid = tid >> 6;
    const int g = lane >> 4;        // edge sub-group 0..3
    const int cl = lane & 15;       // channel lane 0..15
    const int ch = cl * 8;          // owns 8 channels
    const int wave = blockIdx.x * 4 + wid;
    const int nwaves = gridDim.x * 4;

    float cb[8];
    #pragma unroll
    for (int j = 0; j < 8; ++j) cb[j] = convb[ch + j];
    float s[8], q[8];
    #pragma unroll
    for (int j = 0; j < 8; ++j) { s[j] = 0.f; q[j] = 0.f; }

    for (int v = wave; v < N; v += nwaves) {
        const int e0 = rowstart[v], e1 = rowstart[v + 1];
        float a[8];
        #pragma unroll
        for (int j = 0; j < 8; ++j) a[j] = 0.f;
        int e = e0 + g;
        // 2-wide: two independent gathers in flight per iteration
        for (; e + 4 < e1; e += 8) {
            const int u0 = col[e];
            const float w0 = wn[e];
            const int u1 = col[e + 4];
            const float w1 = wn[e + 4];
            uint4 p0 = *(const uint4*)(xw + (size_t)u0 * 128 + ch);
            uint4 p1 = *(const uint4*)(xw + (size_t)u1 * 128 + ch);
            const unsigned int pw0[4] = { p0.x, p0.y, p0.z, p0.w };
            const unsigned int pw1[4] = { p1.x, p1.y, p1.z, p1.w };
            #pragma unroll
            for (int d = 0; d < 4; ++d) {
                a[2 * d]     += w0 * bf2f((unsigned short)(pw0[d] & 0xffff));
                a[2 * d + 1] += w0 * bf2f((unsigned short)(pw0[d] >> 16));
            }
            #pragma unroll
            for (int d = 0; d < 4; ++d) {
                a[2 * d]     += w1 * bf2f((unsigned short)(pw1[d] & 0xffff));
                a[2 * d + 1] += w1 * bf2f((unsigned short)(pw1[d] >> 16));
            }
        }
        if (e < e1) {
            const int u = col[e];
            const float w = wn[e];
            uint4 p = *(const uint4*)(xw + (size_t)u * 128 + ch);
            const unsigned int pw[4] = { p.x, p.y, p.z, p.w };
            #pragma unroll
            for (int d = 0; d < 4; ++d) {
                a[2 * d]     += w * bf2f((unsigned short)(pw[d] & 0xffff));
                a[2 * d + 1] += w * bf2f((unsigned short)(pw[d] >> 16));
            }
        }
        #pragma unroll
        for (int j = 0; j < 8; ++j) {
            a[j] += __shfl_xor(a[j], 16, 64);
            a[j] += __shfl_xor(a[j], 32, 64);
        }
        if (g == 0) {
            const float dv = dis[v];
            const float sw = dv * dv; // self-loop norm
            uint4 p = *(const uint4*)(xw + (size_t)v * 128 + ch);
            const unsigned int pw[4] = { p.x, p.y, p.z, p.w };
            float4 xa = *(const float4*)(x0 + (size_t)v * 128 + ch);
            float4 xb = *(const float4*)(x0 + (size_t)v * 128 + ch + 4);
            const float xr[8] = { xa.x, xa.y, xa.z, xa.w, xb.x, xb.y, xb.z, xb.w };
            float zz[8];
            #pragma unroll
            for (int d = 0; d < 4; ++d) {
                zz[2 * d]     = a[2 * d]     + sw * bf2f((unsigned short)(pw[d] & 0xffff));
                zz[2 * d + 1] = a[2 * d + 1] + sw * bf2f((unsigned short)(pw[d] >> 16));
            }
            #pragma unroll
            for (int j = 0; j < 8; ++j) {
                zz[j] += cb[j] + xr[j];
                s[j] += zz[j];
                q[j] += zz[j] * zz[j];
            }
            *(float4*)(z + (size_t)v * 128 + ch)     = make_float4(zz[0], zz[1], zz[2], zz[3]);
            *(float4*)(z + (size_t)v * 128 + ch + 4) = make_float4(zz[4], zz[5], zz[6], zz[7]);
        }
    }
    if (g == 0) {
        #pragma unroll
        for (int j = 0; j < 8; ++j) { redS[wid][ch + j] = s[j]; redQ[wid][ch + j] = q[j]; }
    }
    __syncthreads();
    if (tid < 128) {
        float ts = redS[0][tid] + redS[1][tid] + redS[2][tid] + redS[3][tid];
        float tq = redQ[0][tid] + redQ[1][tid] + redQ[2][tid] + redQ[3][tid];
        atomicAdd(&bnsum[tid], ts);
        atomicAdd(&bnsq[tid], tq);
    }
}
// fused global_mean_pool + post FFNN (exact fp32)
__global__ __launch_bounds__(128) void k_poolpost(
    const float* __restrict__ x, const int* __restrict__ gstart,
    const float* __restrict__ w1, const float* __restrict__ b1,
    const float* __restrict__ w2, const float* __restrict__ b2,
    float* __restrict__ out, int G)
{
    __shared__ float pr[128], hr[128];
    int g = blockIdx.x, t = threadIdx.x;
    int s = gstart[g], e = gstart[g + 1];
    float acc = 0;
    for (int v = s; v < e; ++v) acc += x[(size_t)v * 128 + t];
    pr[t] = acc / fmaxf((float)(e - s), 1.0f);
    __syncthreads();
    float a = b1[t];
    for (int k = 0; k < 128; ++k) a += pr[k] * w1[k * 128 + t];
    hr[t] = gelu_f(a);
    __syncthreads();
    if (t < 64) {
        float o = b2[t];
        for (int k = 0; k < 128; ++k) o += hr[k] * w2[k * 64 + t];
        out[g * 64 + t] = o;
    }
}

extern "C" void kernel_launch(void* const* d_in, const int* in_sizes, int n_in,
                              void* d_out, int out_size, void* d_ws, size_t ws_size,
                              hipStream_t stream) {
    (void)in_sizes; (void)n_in; (void)out_size; (void)ws_size;
    const float* x_in    = (const float*)d_in[0];
    const int*   ei      = (const int*)d_in[1];
    const int*   batch   = (const int*)d_in[2];
    const float* pre_w1  = (const float*)d_in[3];
    const float* pre_b1  = (const float*)d_in[4];
    const float* pre_w2  = (const float*)d_in[5];
    const float* pre_b2  = (const float*)d_in[6];
    const float* conv_w  = (const float*)d_in[7];
    const float* conv_b  = (const float*)d_in[8];
    const float* ffnn_w1 = (const float*)d_in[9];
    const float* ffnn_b1 = (const float*)d_in[10];
    const float* ffnn_w2 = (const float*)d_in[11];
    const float* ffnn_b2 = (const float*)d_in[12];
    const float* bn_gamma= (const float*)d_in[13];
    const float* bn_beta = (const float*)d_in[14];
    const float* post_w1 = (const float*)d_in[15];
    const float* post_b1 = (const float*)d_in[16];
    const float* post_w2 = (const float*)d_in[17];
    const float* post_b2 = (const float*)d_in[18];
    const int* srcE = ei;
    const int* dstE = ei + EE;

    char* base = (char*)d_ws;
    size_t off = 0;
    auto carve = [&](size_t bytes) {
        char* q = base + off;
        off = (off + bytes + 255) & ~(size_t)255;
        return q;
    };
    float* xf32 = (float*)carve((size_t)NN * 128 * 4);
    float* zf32 = (float*)carve((size_t)NN * 128 * 4);
    unsigned short* xbf = (unsigned short*)carve((size_t)NN * 128 * 2);
    unsigned short* hbf = (unsigned short*)carve((size_t)NN * 128 * 2);
    float* dis   = (float*)carve((size_t)NN * 4);
    int* degi    = (int*)carve((size_t)NN * 4);
    int* fillc   = (int*)carve((size_t)NN * 4);
    int* incl    = (int*)carve((size_t)NN * 4);
    int* bsum    = (int*)carve(64 * 4);
    int* boff    = (int*)carve(64 * 4);
    int* rowstart= (int*)carve((size_t)(NN + 1) * 4);
    int* colx    = (int*)carve((size_t)EE * 4);
    float* wn    = (float*)carve((size_t)EE * 4);
    unsigned short* Wt = (unsigned short*)carve((size_t)8 * 16384 * 2);
    float* bnstat  = (float*)carve(512 * 4); // [hop][sum|sq][128]
    int* gstart    = (int*)carve((size_t)(GG + 1) * 4);

    hipMemsetAsync(degi, 0, (size_t)NN * 4, stream);
    hipMemsetAsync(fillc, 0, (size_t)NN * 4, stream);
    hipMemsetAsync(bnstat, 0, 512 * 4, stream);

    k_deg<<<(EE + 255) / 256, 256, 0, stream>>>(dstE, degi, EE);
    k_dis<<<(NN + 255) / 256, 256, 0, stream>>>(degi, dis, NN);
    const int nsb = (NN + 1023) / 1024;
    k_scan1<<<nsb, 1024, 0, stream>>>(degi, incl, bsum, NN);
    k_scan2<<<1, 1, 0, stream>>>(bsum, boff, nsb);
    k_scan3<<<(NN + 255) / 256, 256, 0, stream>>>(incl, degi, boff, rowstart, NN, EE);
    k_fill<<<(EE + 255) / 256, 256, 0, stream>>>(srcE, dstE, dis, rowstart, fillc, colx, wn, EE);

    k_prepw8<<<512, 256, 0, stream>>>(pre_w1, pre_w2, conv_w, conv_w + 16384,
                                      ffnn_w1, ffnn_w1 + 16384, ffnn_w2, ffnn_w2 + 16384, Wt);
    k_gbounds<<<2, 256, 0, stream>>>(batch, gstart, NN, GG);

    const int gB = (NN + 63) / 64;
    const float invN = 1.0f / NN;
    // preprocess FFNN
    k_gemm<<<gB, 256, 0, stream>>>(x_in, nullptr, Wt + 0 * 16384, pre_b1,
                                   nullptr, nullptr, nullptr, nullptr, invN, 0, 1,
                                   nullptr, 0, nullptr, hbf, NN);
    k_gemm<<<gB, 256, 0, stream>>>(nullptr, hbf, Wt + 1 * 16384, pre_b2,
                                   nullptr, nullptr, nullptr, nullptr, invN, 0, 0,
                                   nullptr, 0, xf32, xbf, NN);
    for (int i = 0; i < 2; ++i) {
        float* bns = bnstat + i * 256;
        float* bnq = bns + 128;
        // xw = x@conv_w
        k_gemm<<<gB, 256, 0, stream>>>(nullptr, xbf, Wt + (2 + i) * 16384, nullptr,
                                       nullptr, nullptr, nullptr, nullptr, invN, 0, 0,
                                       nullptr, 0, nullptr, hbf, NN);
        // z = agg(xw) + conv_b + x ; BN partial stats
        k_agg<<<2048, 256, 0, stream>>>(hbf, rowstart, colx, wn, dis, conv_b + i * 128,
                                        xf32, zf32, bns, bnq, NN);
        // h = gelu(BN(z)@w1+b1)   (BN scale/shift computed in GEMM prologue)
        k_gemm<<<gB, 256, 0, stream>>>(zf32, nullptr, Wt + (4 + i) * 16384, ffnn_b1 + i * 128,
                                       bns, bnq, bn_gamma + i * 128, bn_beta + i * 128, invN, 1, 1,
                                       nullptr, 0, nullptr, hbf, NN);
        // x = h@w2+b2 + BN(z)
        k_gemm<<<gB, 256, 0, stream>>>(nullptr, hbf, Wt + (6 + i) * 16384, ffnn_b2 + i * 128,
                                       bns, bnq, bn_gamma + i * 128, bn_beta + i * 128, invN, 0, 0,
                                       zf32, 1, xf32, xbf, NN);
    }
    k_poolpost<<<GG, 128, 0, stream>>>(xf32, gstart, post_w1, post_b1, post_w2, post_b2,
                                       (float*)d_out, GG);
}

// Round 5
// 441.107 us; speedup vs baseline: 1.5743x; 1.2868x over previous
//
#include <hip/hip_runtime.h>
#include <hip/hip_bf16.h>
#include <math.h>

#define NN 50000
#define EE 800000
#define GG 256

typedef short bf16x8 __attribute__((ext_vector_type(8)));
typedef float f32x4 __attribute__((ext_vector_type(4)));

__device__ __forceinline__ unsigned short f2bf(float x) {
    __hip_bfloat16 h = __float2bfloat16(x);
    union { __hip_bfloat16 h; unsigned short u; } c; c.h = h; return c.u;
}
__device__ __forceinline__ float bf2f(unsigned short u) {
    union { unsigned int v; float f; } t; t.v = ((unsigned int)u) << 16; return t.f;
}
__device__ __forceinline__ float gelu_f(float v) {
    return 0.5f * v * (1.0f + erff(v * 0.70710678118654752f));
}
// XOR swizzle for [rows][128 bf16] LDS tiles (256B row stride)
__device__ __forceinline__ int swz(int row, int bytecol) {
    return row * 256 + (bytecol ^ ((row & 7) << 4));
}

// ---------------- graph prep ----------------
__global__ void k_deg(const int* __restrict__ dst, int* __restrict__ degi, int E) {
    int i = blockIdx.x * blockDim.x + threadIdx.x;
    if (i < E) atomicAdd(&degi[dst[i]], 1);
}
__global__ void k_scan1(const int* __restrict__ degi, int* __restrict__ incl,
                        int* __restrict__ bsum, int N) {
    __shared__ int sm[1024];
    int t = threadIdx.x, i = blockIdx.x * 1024 + t;
    int v = (i < N) ? degi[i] : 0;
    sm[t] = v;
    __syncthreads();
    for (int off = 1; off < 1024; off <<= 1) {
        int add = (t >= off) ? sm[t - off] : 0;
        __syncthreads();
        sm[t] += add;
        __syncthreads();
    }
    if (i < N) incl[i] = sm[t];
    if (t == 1023) bsum[blockIdx.x] = sm[t];
}
// rowstart = exclusive scan (block offset via wave-reduce over bsum) ; + dis
__global__ void k_scan3(const int* __restrict__ incl, const int* __restrict__ degi,
                        const int* __restrict__ bsum, float* __restrict__ dis,
                        int* __restrict__ rowstart, int N, int E, int nsb) {
    __shared__ int sboff;
    int t = threadIdx.x;
    if (t < 64) {
        int nb = blockIdx.x >> 2; // completed 1024-chunks before this 256-block
        int v = (t < nb && t < nsb) ? bsum[t] : 0;
        #pragma unroll
        for (int o = 1; o < 64; o <<= 1) v += __shfl_xor(v, o, 64);
        if (t == 0) sboff = v;
    }
    __syncthreads();
    int i = blockIdx.x * 256 + t;
    if (i < N) {
        rowstart[i] = incl[i] - degi[i] + sboff;
        dis[i] = rsqrtf((float)(degi[i] + 1)); // +1 self loop
    }
    if (i == 0) rowstart[N] = E;
}
__global__ void k_fill(const int* __restrict__ src, const int* __restrict__ dst,
                       const float* __restrict__ dis, const int* __restrict__ rowstart,
                       int* __restrict__ fillc, int* __restrict__ col,
                       float* __restrict__ wn, int E) {
    int i = blockIdx.x * blockDim.x + threadIdx.x;
    if (i < E) {
        int s = src[i], d = dst[i];
        int pos = rowstart[d] + atomicAdd(&fillc[d], 1);
        col[pos] = s;
        wn[pos] = dis[s] * dis[d];
    }
}
// all 8 weight matrices fp32 [k][n] -> bf16 transposed+preswizzled, one launch
__global__ void k_prepw8(const float* __restrict__ w0, const float* __restrict__ w1,
                         const float* __restrict__ w2, const float* __restrict__ w3,
                         const float* __restrict__ w4, const float* __restrict__ w5,
                         const float* __restrict__ w6, const float* __restrict__ w7,
                         unsigned short* __restrict__ Wt) {
    int b = blockIdx.x >> 6;
    const float* W = b == 0 ? w0 : b == 1 ? w1 : b == 2 ? w2 : b == 3 ? w3
                   : b == 4 ? w4 : b == 5 ? w5 : b == 6 ? w6 : w7;
    int tid = (blockIdx.x & 63) * 256 + threadIdx.x; // 0..16383
    int n = tid >> 7, k = tid & 127;
    *(unsigned short*)((char*)(Wt + (size_t)b * 16384) + swz(n, k * 2)) = f2bf(W[k * 128 + n]);
}

// ---------------- fused 3-matmul chain ----------------
// x = [BN](A); h = gelu(x@W1+b1); y = h@W2+b2 [+ BN(A) residual] -> outx32;
// optional stage3: out3 = bf16(y)@W3  (conv for next hop).
// Per-wave 16-row A slab is private -> h and y overwrite As in-place, no sync.
__global__ __launch_bounds__(256) void k_mm(
    const float* __restrict__ A32,
    const unsigned short* __restrict__ W1, const float* __restrict__ b1,
    const unsigned short* __restrict__ W2, const float* __restrict__ b2,
    const unsigned short* __restrict__ W3,
    const float* __restrict__ st_sum, const float* __restrict__ st_sq,
    const float* __restrict__ st_g, const float* __restrict__ st_b,
    float invN, int bn,
    const float* __restrict__ res32,
    float* __restrict__ outx32, unsigned short* __restrict__ out3, int M)
{
    __shared__ unsigned short As[64 * 128];
    __shared__ unsigned short Ws[128 * 128];
    __shared__ float lsc[128], lsh[128];
    const int tid = threadIdx.x;
    const int bm = blockIdx.x * 64;
    if (st_sum && tid < 128) {
        float m = st_sum[tid] * invN;
        float var = st_sq[tid] * invN - m * m;
        float s = st_g[tid] * rsqrtf(var + 1e-5f);
        lsc[tid] = s;
        lsh[tid] = st_b[tid] - m * s;
    }
    __syncthreads(); // lsc/lsh visible before A staging
    { // stage W1
        const uint4* srcp = (const uint4*)W1;
        uint4* dstp = (uint4*)Ws;
        for (int i = tid; i < 2048; i += 256) dstp[i] = srcp[i];
    }
    // stage A (fp32 + optional BN affine), 4 passes of 16 rows
    #pragma unroll
    for (int pass = 0; pass < 4; ++pass) {
        int row = pass * 16 + (tid >> 4);
        int c8 = tid & 15;
        int gr = bm + row; if (gr > M - 1) gr = M - 1;
        const float* pp = A32 + (size_t)gr * 128 + c8 * 8;
        float4 v0 = *(const float4*)pp;
        float4 v1 = *(const float4*)(pp + 4);
        float vv[8] = { v0.x, v0.y, v0.z, v0.w, v1.x, v1.y, v1.z, v1.w };
        if (bn) {
            int ch = c8 * 8;
            #pragma unroll
            for (int j = 0; j < 8; ++j) vv[j] = vv[j] * lsc[ch + j] + lsh[ch + j];
        }
        unsigned short tmp[8];
        #pragma unroll
        for (int j = 0; j < 8; ++j) tmp[j] = f2bf(vv[j]);
        *(uint4*)((char*)As + swz(row, c8 * 16)) = *(uint4*)tmp;
    }
    __syncthreads();

    const int lane = tid & 63, wid = tid >> 6;
    const int r0 = wid * 16;
    const int lrow = lane & 15;
    const int lkb = (lane >> 4) * 16;
    const int cb = lane & 15;
    const int rb = r0 + (lane >> 4) * 4;

    f32x4 acc[8];
    // ---- mm1 ----
    #pragma unroll
    for (int n = 0; n < 8; ++n) acc[n] = (f32x4){0.f, 0.f, 0.f, 0.f};
    #pragma unroll
    for (int kk = 0; kk < 4; ++kk) {
        int bc = kk * 64 + lkb;
        bf16x8 a = *(const bf16x8*)((const char*)As + swz(r0 + lrow, bc));
        #pragma unroll
        for (int n = 0; n < 8; ++n) {
            bf16x8 b = *(const bf16x8*)((const char*)Ws + swz(n * 16 + lrow, bc));
            acc[n] = __builtin_amdgcn_mfma_f32_16x16x32_bf16(a, b, acc[n], 0, 0, 0);
        }
    }
    // epi1: gelu -> h into own As slab (rows rb..rb+3 are wave-private)
    #pragma unroll
    for (int n = 0; n < 8; ++n) {
        int colg = n * 16 + cb;
        float bv = b1[colg];
        #pragma unroll
        for (int j = 0; j < 4; ++j) {
            float v = gelu_f(acc[n][j] + bv);
            *(unsigned short*)((char*)As + swz(rb + j, colg * 2)) = f2bf(v);
        }
    }
    __syncthreads(); // all waves done reading W1
    { // stage W2
        const uint4* srcp = (const uint4*)W2;
        uint4* dstp = (uint4*)Ws;
        for (int i = tid; i < 2048; i += 256) dstp[i] = srcp[i];
    }
    __syncthreads();
    // ---- mm2 ----
    #pragma unroll
    for (int n = 0; n < 8; ++n) acc[n] = (f32x4){0.f, 0.f, 0.f, 0.f};
    #pragma unroll
    for (int kk = 0; kk < 4; ++kk) {
        int bc = kk * 64 + lkb;
        bf16x8 a = *(const bf16x8*)((const char*)As + swz(r0 + lrow, bc));
        #pragma unroll
        for (int n = 0; n < 8; ++n) {
            bf16x8 b = *(const bf16x8*)((const char*)Ws + swz(n * 16 + lrow, bc));
            acc[n] = __builtin_amdgcn_mfma_f32_16x16x32_bf16(a, b, acc[n], 0, 0, 0);
        }
    }
    // epi2: + b2 (+BN residual) -> outx32; bf16 copy into As for stage3
    #pragma unroll
    for (int n = 0; n < 8; ++n) {
        int colg = n * 16 + cb;
        float bv = b2[colg];
        #pragma unroll
        for (int j = 0; j < 4; ++j) {
            int rowg = bm + rb + j;
            float v = acc[n][j] + bv;
            if (res32) {
                float r = res32[(size_t)((rowg < M) ? rowg : (M - 1)) * 128 + colg];
                if (bn) r = r * lsc[colg] + lsh[colg];
                v += r;
            }
            if (rowg < M) outx32[(size_t)rowg * 128 + colg] = v;
            if (W3) *(unsigned short*)((char*)As + swz(rb + j, colg * 2)) = f2bf(v);
        }
    }
    if (!W3) return;
    __syncthreads(); // all waves done reading W2
    { // stage W3
        const uint4* srcp = (const uint4*)W3;
        uint4* dstp = (uint4*)Ws;
        for (int i = tid; i < 2048; i += 256) dstp[i] = srcp[i];
    }
    __syncthreads();
    // ---- mm3 (conv) ----
    #pragma unroll
    for (int n = 0; n < 8; ++n) acc[n] = (f32x4){0.f, 0.f, 0.f, 0.f};
    #pragma unroll
    for (int kk = 0; kk < 4; ++kk) {
        int bc = kk * 64 + lkb;
        bf16x8 a = *(const bf16x8*)((const char*)As + swz(r0 + lrow, bc));
        #pragma unroll
        for (int n = 0; n < 8; ++n) {
            bf16x8 b = *(const bf16x8*)((const char*)Ws + swz(n * 16 + lrow, bc));
            acc[n] = __builtin_amdgcn_mfma_f32_16x16x32_bf16(a, b, acc[n], 0, 0, 0);
        }
    }
    #pragma unroll
    for (int n = 0; n < 8; ++n) {
        int colg = n * 16 + cb;
        #pragma unroll
        for (int j = 0; j < 4; ++j) {
            int rowg = bm + rb + j;
            if (rowg < M) out3[(size_t)rowg * 128 + colg] = f2bf(acc[n][j]);
        }
    }
}

// ---------------- CSR aggregation + residual + BN partial stats ----------------
// (frozen from round 4 — at structural gather floor)
__global__ __launch_bounds__(256) void k_agg(
    const unsigned short* __restrict__ xw, const int* __restrict__ rowstart,
    const int* __restrict__ col, const float* __restrict__ wn,
    const float* __restrict__ dis, const float* __restrict__ convb,
    const float* __restrict__ x0, float* __restrict__ z,
    float* __restrict__ bnsum, float* __restrict__ bnsq, int N)
{
    __shared__ float redS[4][128];
    __shared__ float redQ[4][128];
    const int tid = threadIdx.x;
    const int lane = tid & 63;
    const int wid = tid >> 6;
    const int g = lane >> 4;
    const int cl = lane & 15;
    const int ch = cl * 8;
    const int wave = blockIdx.x * 4 + wid;
    const int nwaves = gridDim.x * 4;

    float cb[8];
    #pragma unroll
    for (int j = 0; j < 8; ++j) cb[j] = convb[ch + j];
    float s[8], q[8];
    #pragma unroll
    for (int j = 0; j < 8; ++j) { s[j] = 0.f; q[j] = 0.f; }

    for (int v = wave; v < N; v += nwaves) {
        const int e0 = rowstart[v], e1 = rowstart[v + 1];
        float a[8];
        #pragma unroll
        for (int j = 0; j < 8; ++j) a[j] = 0.f;
        int e = e0 + g;
        for (; e + 4 < e1; e += 8) {
            const int u0 = col[e];
            const float w0 = wn[e];
            const int u1 = col[e + 4];
            const float w1 = wn[e + 4];
            uint4 p0 = *(const uint4*)(xw + (size_t)u0 * 128 + ch);
            uint4 p1 = *(const uint4*)(xw + (size_t)u1 * 128 + ch);
            const unsigned int pw0[4] = { p0.x, p0.y, p0.z, p0.w };
            const unsigned int pw1[4] = { p1.x, p1.y, p1.z, p1.w };
            #pragma unroll
            for (int d = 0; d < 4; ++d) {
                a[2 * d]     += w0 * bf2f((unsigned short)(pw0[d] & 0xffff));
                a[2 * d + 1] += w0 * bf2f((unsigned short)(pw0[d] >> 16));
            }
            #pragma unroll
            for (int d = 0; d < 4; ++d) {
                a[2 * d]     += w1 * bf2f((unsigned short)(pw1[d] & 0xffff));
                a[2 * d + 1] += w1 * bf2f((unsigned short)(pw1[d] >> 16));
            }
        }
        if (e < e1) {
            const int u = col[e];
            const float w = wn[e];
            uint4 p = *(const uint4*)(xw + (size_t)u * 128 + ch);
            const unsigned int pw[4] = { p.x, p.y, p.z, p.w };
            #pragma unroll
            for (int d = 0; d < 4; ++d) {
                a[2 * d]     += w * bf2f((unsigned short)(pw[d] & 0xffff));
                a[2 * d + 1] += w * bf2f((unsigned short)(pw[d] >> 16));
            }
        }
        #pragma unroll
        for (int j = 0; j < 8; ++j) {
            a[j] += __shfl_xor(a[j], 16, 64);
            a[j] += __shfl_xor(a[j], 32, 64);
        }
        if (g == 0) {
            const float dv = dis[v];
            const float sw = dv * dv;
            uint4 p = *(const uint4*)(xw + (size_t)v * 128 + ch);
            const unsigned int pw[4] = { p.x, p.y, p.z, p.w };
            float4 xa = *(const float4*)(x0 + (size_t)v * 128 + ch);
            float4 xb = *(const float4*)(x0 + (size_t)v * 128 + ch + 4);
            const float xr[8] = { xa.x, xa.y, xa.z, xa.w, xb.x, xb.y, xb.z, xb.w };
            float zz[8];
            #pragma unroll
            for (int d = 0; d < 4; ++d) {
                zz[2 * d]     = a[2 * d]     + sw * bf2f((unsigned short)(pw[d] & 0xffff));
                zz[2 * d + 1] = a[2 * d + 1] + sw * bf2f((unsigned short)(pw[d] >> 16));
            }
            #pragma unroll
            for (int j = 0; j < 8; ++j) {
                zz[j] += cb[j] + xr[j];
                s[j] += zz[j];
                q[j] += zz[j] * zz[j];
            }
            *(float4*)(z + (size_t)v * 128 + ch)     = make_float4(zz[0], zz[1], zz[2], zz[3]);
            *(float4*)(z + (size_t)v * 128 + ch + 4) = make_float4(zz[4], zz[5], zz[6], zz[7]);
        }
    }
    if (g == 0) {
        #pragma unroll
        for (int j = 0; j < 8; ++j) { redS[wid][ch + j] = s[j]; redQ[wid][ch + j] = q[j]; }
    }
    __syncthreads();
    if (tid < 128) {
        float ts = redS[0][tid] + redS[1][tid] + redS[2][tid] + redS[3][tid];
        float tq = redQ[0][tid] + redQ[1][tid] + redQ[2][tid] + redQ[3][tid];
        atomicAdd(&bnsum[tid], ts);
        atomicAdd(&bnsq[tid], tq);
    }
}
// fused group-bounds + global_mean_pool + post FFNN (exact fp32)
__global__ __launch_bounds__(128) void k_poolpost(
    const float* __restrict__ x, const int* __restrict__ batch,
    const float* __restrict__ w1, const float* __restrict__ b1,
    const float* __restrict__ w2, const float* __restrict__ b2,
    float* __restrict__ out, int N, int G)
{
    __shared__ float pr[128], hr[128];
    __shared__ int bounds[2];
    int g = blockIdx.x, t = threadIdx.x;
    if (t < 2) {
        int tgt = g + t, lo = 0, hi = N;
        while (lo < hi) { int mid = (lo + hi) >> 1; if (batch[mid] < tgt) lo = mid + 1; else hi = mid; }
        bounds[t] = lo;
    }
    __syncthreads();
    int s = bounds[0], e = bounds[1];
    float acc = 0;
    for (int v = s; v < e; ++v) acc += x[(size_t)v * 128 + t];
    pr[t] = acc / fmaxf((float)(e - s), 1.0f);
    __syncthreads();
    float a = b1[t];
    for (int k = 0; k < 128; ++k) a += pr[k] * w1[k * 128 + t];
    hr[t] = gelu_f(a);
    __syncthreads();
    if (t < 64) {
        float o = b2[t];
        for (int k = 0; k < 128; ++k) o += hr[k] * w2[k * 64 + t];
        out[g * 64 + t] = o;
    }
}

extern "C" void kernel_launch(void* const* d_in, const int* in_sizes, int n_in,
                              void* d_out, int out_size, void* d_ws, size_t ws_size,
                              hipStream_t stream) {
    (void)in_sizes; (void)n_in; (void)out_size; (void)ws_size;
    const float* x_in    = (const float*)d_in[0];
    const int*   ei      = (const int*)d_in[1];
    const int*   batch   = (const int*)d_in[2];
    const float* pre_w1  = (const float*)d_in[3];
    const float* pre_b1  = (const float*)d_in[4];
    const float* pre_w2  = (const float*)d_in[5];
    const float* pre_b2  = (const float*)d_in[6];
    const float* conv_w  = (const float*)d_in[7];
    const float* conv_b  = (const float*)d_in[8];
    const float* ffnn_w1 = (const float*)d_in[9];
    const float* ffnn_b1 = (const float*)d_in[10];
    const float* ffnn_w2 = (const float*)d_in[11];
    const float* ffnn_b2 = (const float*)d_in[12];
    const float* bn_gamma= (const float*)d_in[13];
    const float* bn_beta = (const float*)d_in[14];
    const float* post_w1 = (const float*)d_in[15];
    const float* post_b1 = (const float*)d_in[16];
    const float* post_w2 = (const float*)d_in[17];
    const float* post_b2 = (const float*)d_in[18];
    const int* srcE = ei;
    const int* dstE = ei + EE;

    char* base = (char*)d_ws;
    size_t off = 0;
    auto carve = [&](size_t bytes) {
        char* q = base + off;
        off = (off + bytes + 255) & ~(size_t)255;
        return q;
    };
    float* xf32 = (float*)carve((size_t)NN * 128 * 4);
    float* zf32 = (float*)carve((size_t)NN * 128 * 4);
    unsigned short* hbf = (unsigned short*)carve((size_t)NN * 128 * 2); // xw scratch
    float* dis   = (float*)carve((size_t)NN * 4);
    // zero-region: degi, fillc, bnstat carved contiguously -> ONE memset
    int*   degi  = (int*)carve((size_t)NN * 4);
    int*   fillc = (int*)carve((size_t)NN * 4);
    float* bnstat= (float*)carve(512 * 4); // [hop][sum|sq][128]
    size_t zlen  = (size_t)((char*)(bnstat + 512) - (char*)degi);
    int* incl    = (int*)carve((size_t)NN * 4);
    int* bsum    = (int*)carve(64 * 4);
    int* rowstart= (int*)carve((size_t)(NN + 1) * 4);
    int* colx    = (int*)carve((size_t)EE * 4);
    float* wn    = (float*)carve((size_t)EE * 4);
    unsigned short* Wt = (unsigned short*)carve((size_t)8 * 16384 * 2);

    hipMemsetAsync(degi, 0, zlen, stream);

    const int nsb = (NN + 1023) / 1024;
    k_deg<<<(EE + 255) / 256, 256, 0, stream>>>(dstE, degi, EE);
    k_scan1<<<nsb, 1024, 0, stream>>>(degi, incl, bsum, NN);
    k_scan3<<<(NN + 255) / 256, 256, 0, stream>>>(incl, degi, bsum, dis, rowstart, NN, EE, nsb);
    k_fill<<<(EE + 255) / 256, 256, 0, stream>>>(srcE, dstE, dis, rowstart, fillc, colx, wn, EE);
    k_prepw8<<<512, 256, 0, stream>>>(pre_w1, pre_w2, conv_w, conv_w + 16384,
                                      ffnn_w1, ffnn_w1 + 16384, ffnn_w2, ffnn_w2 + 16384, Wt);

    const int gB = (NN + 63) / 64;
    const float invN = 1.0f / NN;
    // preprocess FFNN + conv0:  x = ffnn(x_in) -> xf32 ; xw0 = x@conv_w0 -> hbf
    k_mm<<<gB, 256, 0, stream>>>(x_in, Wt + 0 * 16384, pre_b1, Wt + 1 * 16384, pre_b2,
                                 Wt + 2 * 16384, nullptr, nullptr, nullptr, nullptr,
                                 invN, 0, nullptr, xf32, hbf, NN);
    // hop 0
    k_agg<<<2048, 256, 0, stream>>>(hbf, rowstart, colx, wn, dis, conv_b,
                                    xf32, zf32, bnstat, bnstat + 128, NN);
    k_mm<<<gB, 256, 0, stream>>>(zf32, Wt + 4 * 16384, ffnn_b1, Wt + 6 * 16384, ffnn_b2,
                                 Wt + 3 * 16384, bnstat, bnstat + 128, bn_gamma, bn_beta,
                                 invN, 1, zf32, xf32, hbf, NN);
    // hop 1
    k_agg<<<2048, 256, 0, stream>>>(hbf, rowstart, colx, wn, dis, conv_b + 128,
                                    xf32, zf32, bnstat + 256, bnstat + 384, NN);
    k_mm<<<gB, 256, 0, stream>>>(zf32, Wt + 5 * 16384, ffnn_b1 + 128, Wt + 7 * 16384, ffnn_b2 + 128,
                                 nullptr, bnstat + 256, bnstat + 384, bn_gamma + 128, bn_beta + 128,
                                 invN, 1, zf32, xf32, nullptr, NN);
    // pool + post
    k_poolpost<<<GG, 128, 0, stream>>>(xf32, batch, post_w1, post_b1, post_w2, post_b2,
                                       (float*)d_out, NN, GG);
}

// Round 7
// 396.559 us; speedup vs baseline: 1.7511x; 1.1123x over previous
//
#include <hip/hip_runtime.h>
#include <hip/hip_bf16.h>
#include <math.h>

#define NN 50000
#define EE 800000
#define GG 256

typedef short bf16x8 __attribute__((ext_vector_type(8)));
typedef float f32x4 __attribute__((ext_vector_type(4)));
typedef unsigned int u32x4 __attribute__((ext_vector_type(4)));

__device__ __forceinline__ unsigned short f2bf(float x) {
    __hip_bfloat16 h = __float2bfloat16(x);
    union { __hip_bfloat16 h; unsigned short u; } c; c.h = h; return c.u;
}
__device__ __forceinline__ float bf2f(unsigned short u) {
    union { unsigned int v; float f; } t; t.v = ((unsigned int)u) << 16; return t.f;
}
__device__ __forceinline__ float gelu_f(float v) {
    return 0.5f * v * (1.0f + erff(v * 0.70710678118654752f));
}
// XOR swizzle for [rows][128 bf16] LDS tiles (256B row stride)
__device__ __forceinline__ int swz(int row, int bytecol) {
    return row * 256 + (bytecol ^ ((row & 7) << 4));
}

// ---------------- graph prep ----------------
__global__ void k_deg(const int* __restrict__ dst, int* __restrict__ degi, int E) {
    int i = blockIdx.x * blockDim.x + threadIdx.x;
    if (i < E) atomicAdd(&degi[dst[i]], 1);
}
__global__ void k_scan1(const int* __restrict__ degi, int* __restrict__ incl,
                        int* __restrict__ bsum, int N) {
    __shared__ int sm[1024];
    int t = threadIdx.x, i = blockIdx.x * 1024 + t;
    int v = (i < N) ? degi[i] : 0;
    sm[t] = v;
    __syncthreads();
    for (int off = 1; off < 1024; off <<= 1) {
        int add = (t >= off) ? sm[t - off] : 0;
        __syncthreads();
        sm[t] += add;
        __syncthreads();
    }
    if (i < N) incl[i] = sm[t];
    if (t == 1023) bsum[blockIdx.x] = sm[t];
}
// rowstart = exclusive scan (block offset via wave-reduce over bsum) ; + dis
__global__ void k_scan3(const int* __restrict__ incl, const int* __restrict__ degi,
                        const int* __restrict__ bsum, float* __restrict__ dis,
                        int* __restrict__ rowstart, int N, int E, int nsb) {
    __shared__ int sboff;
    int t = threadIdx.x;
    if (t < 64) {
        int nb = blockIdx.x >> 2;
        int v = (t < nb && t < nsb) ? bsum[t] : 0;
        #pragma unroll
        for (int o = 1; o < 64; o <<= 1) v += __shfl_xor(v, o, 64);
        if (t == 0) sboff = v;
    }
    __syncthreads();
    int i = blockIdx.x * 256 + t;
    if (i < N) {
        rowstart[i] = incl[i] - degi[i] + sboff;
        dis[i] = rsqrtf((float)(degi[i] + 1)); // +1 self loop
    }
    if (i == 0) rowstart[N] = E;
}
__global__ void k_fill(const int* __restrict__ src, const int* __restrict__ dst,
                       const float* __restrict__ dis, const int* __restrict__ rowstart,
                       int* __restrict__ fillc, int* __restrict__ col,
                       float* __restrict__ wn, int E) {
    int i = blockIdx.x * blockDim.x + threadIdx.x;
    if (i < E) {
        int s = src[i], d = dst[i];
        int pos = rowstart[d] + atomicAdd(&fillc[d], 1);
        col[pos] = s;
        wn[pos] = dis[s] * dis[d];
    }
}
// all 8 weight matrices fp32 [k][n] -> bf16 transposed+preswizzled, one launch
__global__ void k_prepw8(const float* __restrict__ w0, const float* __restrict__ w1,
                         const float* __restrict__ w2, const float* __restrict__ w3,
                         const float* __restrict__ w4, const float* __restrict__ w5,
                         const float* __restrict__ w6, const float* __restrict__ w7,
                         unsigned short* __restrict__ Wt) {
    int b = blockIdx.x >> 6;
    const float* W = b == 0 ? w0 : b == 1 ? w1 : b == 2 ? w2 : b == 3 ? w3
                   : b == 4 ? w4 : b == 5 ? w5 : b == 6 ? w6 : w7;
    int tid = (blockIdx.x & 63) * 256 + threadIdx.x;
    int n = tid >> 7, k = tid & 127;
    *(unsigned short*)((char*)(Wt + (size_t)b * 16384) + swz(n, k * 2)) = f2bf(W[k * 128 + n]);
}

// ---------------- fused 3-matmul chain ----------------
// x' = [BN](A); h = gelu(x'@W1+b1); y = h@W2+b2 [+ x' residual from regs] -> outx32;
// optional stage3: out3 = bf16(y)@W3  (conv for next hop).
__global__ __launch_bounds__(256) void k_mm(
    const float* __restrict__ A32, const unsigned short* __restrict__ A16,
    const unsigned short* __restrict__ W1, const float* __restrict__ b1,
    const unsigned short* __restrict__ W2, const float* __restrict__ b2,
    const unsigned short* __restrict__ W3,
    const float* __restrict__ st_sum, const float* __restrict__ st_sq,
    const float* __restrict__ st_g, const float* __restrict__ st_b,
    float invN, int bn, int hasres,
    float* __restrict__ outx32, unsigned short* __restrict__ out3, int M)
{
    __shared__ unsigned short As[64 * 128];
    __shared__ unsigned short Ws[128 * 128];
    __shared__ float lsc[128], lsh[128];
    const int tid = threadIdx.x;
    const int bm = blockIdx.x * 64;
    if (st_sum && tid < 128) {
        float m = st_sum[tid] * invN;
        float var = st_sq[tid] * invN - m * m;
        float s = st_g[tid] * rsqrtf(var + 1e-5f);
        lsc[tid] = s;
        lsh[tid] = st_b[tid] - m * s;
    }
    __syncthreads();
    { // stage W1
        const uint4* srcp = (const uint4*)W1;
        uint4* dstp = (uint4*)Ws;
        for (int i = tid; i < 2048; i += 256) dstp[i] = srcp[i];
    }
    // stage A, 4 passes of 16 rows; optional BN affine
    #pragma unroll
    for (int pass = 0; pass < 4; ++pass) {
        int row = pass * 16 + (tid >> 4);
        int c8 = tid & 15;
        int gr = bm + row; if (gr > M - 1) gr = M - 1;
        float vv[8];
        if (A32) {
            const float* pp = A32 + (size_t)gr * 128 + c8 * 8;
            float4 v0 = *(const float4*)pp;
            float4 v1 = *(const float4*)(pp + 4);
            vv[0] = v0.x; vv[1] = v0.y; vv[2] = v0.z; vv[3] = v0.w;
            vv[4] = v1.x; vv[5] = v1.y; vv[6] = v1.z; vv[7] = v1.w;
        } else {
            u32x4 raw = __builtin_nontemporal_load((const u32x4*)(A16 + (size_t)gr * 128 + c8 * 8));
            #pragma unroll
            for (int d = 0; d < 4; ++d) {
                vv[2 * d]     = bf2f((unsigned short)(raw[d] & 0xffff));
                vv[2 * d + 1] = bf2f((unsigned short)(raw[d] >> 16));
            }
        }
        if (bn) {
            int ch = c8 * 8;
            #pragma unroll
            for (int j = 0; j < 8; ++j) vv[j] = vv[j] * lsc[ch + j] + lsh[ch + j];
        }
        unsigned short tmp[8];
        #pragma unroll
        for (int j = 0; j < 8; ++j) tmp[j] = f2bf(vv[j]);
        *(uint4*)((char*)As + swz(row, c8 * 16)) = *(uint4*)tmp;
    }
    __syncthreads();

    const int lane = tid & 63, wid = tid >> 6;
    const int r0 = wid * 16;
    const int lrow = lane & 15;
    const int lkb = (lane >> 4) * 16;
    const int cb = lane & 15;
    const int rb = r0 + (lane >> 4) * 4;

    f32x4 acc[8];
    // ---- mm1 ----
    #pragma unroll
    for (int n = 0; n < 8; ++n) acc[n] = (f32x4){0.f, 0.f, 0.f, 0.f};
    #pragma unroll
    for (int kk = 0; kk < 4; ++kk) {
        int bc = kk * 64 + lkb;
        bf16x8 a = *(const bf16x8*)((const char*)As + swz(r0 + lrow, bc));
        #pragma unroll
        for (int n = 0; n < 8; ++n) {
            bf16x8 b = *(const bf16x8*)((const char*)Ws + swz(n * 16 + lrow, bc));
            acc[n] = __builtin_amdgcn_mfma_f32_16x16x32_bf16(a, b, acc[n], 0, 0, 0);
        }
    }
    // capture residual x' (BN'd A) from own epilogue slots BEFORE epi1 overwrites
    unsigned short rres[32];
    if (hasres) {
        #pragma unroll
        for (int n = 0; n < 8; ++n)
            #pragma unroll
            for (int j = 0; j < 4; ++j)
                rres[n * 4 + j] = *(const unsigned short*)((const char*)As + swz(rb + j, (n * 16 + cb) * 2));
    }
    // epi1: gelu -> h into own As slab (rows rb..rb+3 are wave-private)
    #pragma unroll
    for (int n = 0; n < 8; ++n) {
        int colg = n * 16 + cb;
        float bv = b1[colg];
        #pragma unroll
        for (int j = 0; j < 4; ++j) {
            float v = gelu_f(acc[n][j] + bv);
            *(unsigned short*)((char*)As + swz(rb + j, colg * 2)) = f2bf(v);
        }
    }
    __syncthreads(); // all waves done reading W1
    { // stage W2
        const uint4* srcp = (const uint4*)W2;
        uint4* dstp = (uint4*)Ws;
        for (int i = tid; i < 2048; i += 256) dstp[i] = srcp[i];
    }
    __syncthreads();
    // ---- mm2 ----
    #pragma unroll
    for (int n = 0; n < 8; ++n) acc[n] = (f32x4){0.f, 0.f, 0.f, 0.f};
    #pragma unroll
    for (int kk = 0; kk < 4; ++kk) {
        int bc = kk * 64 + lkb;
        bf16x8 a = *(const bf16x8*)((const char*)As + swz(r0 + lrow, bc));
        #pragma unroll
        for (int n = 0; n < 8; ++n) {
            bf16x8 b = *(const bf16x8*)((const char*)Ws + swz(n * 16 + lrow, bc));
            acc[n] = __builtin_amdgcn_mfma_f32_16x16x32_bf16(a, b, acc[n], 0, 0, 0);
        }
    }
    // epi2: + b2 (+ register residual) -> outx32; bf16 copy into As for stage3
    #pragma unroll
    for (int n = 0; n < 8; ++n) {
        int colg = n * 16 + cb;
        float bv = b2[colg];
        #pragma unroll
        for (int j = 0; j < 4; ++j) {
            int rowg = bm + rb + j;
            float v = acc[n][j] + bv;
            if (hasres) v += bf2f(rres[n * 4 + j]);
            if (rowg < M) outx32[(size_t)rowg * 128 + colg] = v;
            if (W3) *(unsigned short*)((char*)As + swz(rb + j, colg * 2)) = f2bf(v);
        }
    }
    if (!W3) return;
    __syncthreads(); // all waves done reading W2
    { // stage W3
        const uint4* srcp = (const uint4*)W3;
        uint4* dstp = (uint4*)Ws;
        for (int i = tid; i < 2048; i += 256) dstp[i] = srcp[i];
    }
    __syncthreads();
    // ---- mm3 (conv) ----
    #pragma unroll
    for (int n = 0; n < 8; ++n) acc[n] = (f32x4){0.f, 0.f, 0.f, 0.f};
    #pragma unroll
    for (int kk = 0; kk < 4; ++kk) {
        int bc = kk * 64 + lkb;
        bf16x8 a = *(const bf16x8*)((const char*)As + swz(r0 + lrow, bc));
        #pragma unroll
        for (int n = 0; n < 8; ++n) {
            bf16x8 b = *(const bf16x8*)((const char*)Ws + swz(n * 16 + lrow, bc));
            acc[n] = __builtin_amdgcn_mfma_f32_16x16x32_bf16(a, b, acc[n], 0, 0, 0);
        }
    }
    #pragma unroll
    for (int n = 0; n < 8; ++n) {
        int colg = n * 16 + cb;
        #pragma unroll
        for (int j = 0; j < 4; ++j) {
            int rowg = bm + rb + j;
            if (rowg < M) out3[(size_t)rowg * 128 + colg] = f2bf(acc[n][j]);
        }
    }
}

// ---------------- CSR aggregation + residual + BN partial stats ----------------
// Streams (col/wn/x0 reads, z write) are non-temporal to preserve xw in L2.
// z written as bf16 (stats stay fp32, computed pre-rounding).
__global__ __launch_bounds__(256) void k_agg(
    const unsigned short* __restrict__ xw, const int* __restrict__ rowstart,
    const int* __restrict__ col, const float* __restrict__ wn,
    const float* __restrict__ dis, const float* __restrict__ convb,
    const float* __restrict__ x0, unsigned short* __restrict__ zbf,
    float* __restrict__ bnsum, float* __restrict__ bnsq, int N)
{
    __shared__ float redS[4][128];
    __shared__ float redQ[4][128];
    const int tid = threadIdx.x;
    const int lane = tid & 63;
    const int wid = tid >> 6;
    const int g = lane >> 4;
    const int cl = lane & 15;
    const int ch = cl * 8;
    const int wave = blockIdx.x * 4 + wid;
    const int nwaves = gridDim.x * 4;

    float cb[8];
    #pragma unroll
    for (int j = 0; j < 8; ++j) cb[j] = convb[ch + j];
    float s[8], q[8];
    #pragma unroll
    for (int j = 0; j < 8; ++j) { s[j] = 0.f; q[j] = 0.f; }

    for (int v = wave; v < N; v += nwaves) {
        const int e0 = rowstart[v], e1 = rowstart[v + 1];
        float a[8];
        #pragma unroll
        for (int j = 0; j < 8; ++j) a[j] = 0.f;
        int e = e0 + g;
        for (; e + 4 < e1; e += 8) {
            const int u0 = __builtin_nontemporal_load(col + e);
            const float w0 = __builtin_nontemporal_load(wn + e);
            const int u1 = __builtin_nontemporal_load(col + e + 4);
            const float w1 = __builtin_nontemporal_load(wn + e + 4);
            u32x4 p0 = *(const u32x4*)(xw + (size_t)u0 * 128 + ch);
            u32x4 p1 = *(const u32x4*)(xw + (size_t)u1 * 128 + ch);
            #pragma unroll
            for (int d = 0; d < 4; ++d) {
                a[2 * d]     += w0 * bf2f((unsigned short)(p0[d] & 0xffff));
                a[2 * d + 1] += w0 * bf2f((unsigned short)(p0[d] >> 16));
            }
            #pragma unroll
            for (int d = 0; d < 4; ++d) {
                a[2 * d]     += w1 * bf2f((unsigned short)(p1[d] & 0xffff));
                a[2 * d + 1] += w1 * bf2f((unsigned short)(p1[d] >> 16));
            }
        }
        if (e < e1) {
            const int u = __builtin_nontemporal_load(col + e);
            const float w = __builtin_nontemporal_load(wn + e);
            u32x4 p = *(const u32x4*)(xw + (size_t)u * 128 + ch);
            #pragma unroll
            for (int d = 0; d < 4; ++d) {
                a[2 * d]     += w * bf2f((unsigned short)(p[d] & 0xffff));
                a[2 * d + 1] += w * bf2f((unsigned short)(p[d] >> 16));
            }
        }
        #pragma unroll
        for (int j = 0; j < 8; ++j) {
            a[j] += __shfl_xor(a[j], 16, 64);
            a[j] += __shfl_xor(a[j], 32, 64);
        }
        if (g == 0) {
            const float dv = dis[v];
            const float sw = dv * dv;
            u32x4 p = *(const u32x4*)(xw + (size_t)v * 128 + ch);
            f32x4 xa = __builtin_nontemporal_load((const f32x4*)(x0 + (size_t)v * 128 + ch));
            f32x4 xb = __builtin_nontemporal_load((const f32x4*)(x0 + (size_t)v * 128 + ch + 4));
            const float xr[8] = { xa[0], xa[1], xa[2], xa[3], xb[0], xb[1], xb[2], xb[3] };
            float zz[8];
            #pragma unroll
            for (int d = 0; d < 4; ++d) {
                zz[2 * d]     = a[2 * d]     + sw * bf2f((unsigned short)(p[d] & 0xffff));
                zz[2 * d + 1] = a[2 * d + 1] + sw * bf2f((unsigned short)(p[d] >> 16));
            }
            unsigned short zo[8];
            #pragma unroll
            for (int j = 0; j < 8; ++j) {
                zz[j] += cb[j] + xr[j];
                s[j] += zz[j];
                q[j] += zz[j] * zz[j];
                zo[j] = f2bf(zz[j]);
            }
            __builtin_nontemporal_store(*(const u32x4*)zo, (u32x4*)(zbf + (size_t)v * 128 + ch));
        }
    }
    if (g == 0) {
        #pragma unroll
        for (int j = 0; j < 8; ++j) { redS[wid][ch + j] = s[j]; redQ[wid][ch + j] = q[j]; }
    }
    __syncthreads();
    if (tid < 128) {
        float ts = redS[0][tid] + redS[1][tid] + redS[2][tid] + redS[3][tid];
        float tq = redQ[0][tid] + redQ[1][tid] + redQ[2][tid] + redQ[3][tid];
        atomicAdd(&bnsum[tid], ts);
        atomicAdd(&bnsq[tid], tq);
    }
}
// node-partitioned pooling: per-block partial sums flushed via atomics
__global__ __launch_bounds__(128) void k_pool(
    const float* __restrict__ x, const int* __restrict__ batch,
    float* __restrict__ pooled, int* __restrict__ cnt, int N)
{
    const int t = threadIdx.x;
    const int per = (N + gridDim.x - 1) / gridDim.x;
    const int s = blockIdx.x * per;
    const int e = min(s + per, N);
    if (s >= e) return;
    float acc = 0.f;
    int gcur = batch[s];
    int run = 0;
    for (int v = s; v < e; ++v) {
        int g = batch[v];
        if (g != gcur) {
            atomicAdd(&pooled[(size_t)gcur * 128 + t], acc);
            if (t == 0) atomicAdd(&cnt[gcur], run);
            acc = 0.f; run = 0; gcur = g;
        }
        acc += __builtin_nontemporal_load(x + (size_t)v * 128 + t);
        ++run;
    }
    atomicAdd(&pooled[(size_t)gcur * 128 + t], acc);
    if (t == 0) atomicAdd(&cnt[gcur], run);
}
// post FFNN (exact fp32)
__global__ __launch_bounds__(128) void k_post(
    const float* __restrict__ pooled, const int* __restrict__ cnt,
    const float* __restrict__ w1, const float* __restrict__ b1,
    const float* __restrict__ w2, const float* __restrict__ b2,
    float* __restrict__ out, int G)
{
    __shared__ float pr[128], hr[128];
    int g = blockIdx.x, t = threadIdx.x;
    float c = fmaxf((float)cnt[g], 1.0f);
    pr[t] = pooled[(size_t)g * 128 + t] / c;
    __syncthreads();
    float a = b1[t];
    for (int k = 0; k < 128; ++k) a += pr[k] * w1[k * 128 + t];
    hr[t] = gelu_f(a);
    __syncthreads();
    if (t < 64) {
        float o = b2[t];
        for (int k = 0; k < 128; ++k) o += hr[k] * w2[k * 64 + t];
        out[g * 64 + t] = o;
    }
}

extern "C" void kernel_launch(void* const* d_in, const int* in_sizes, int n_in,
                              void* d_out, int out_size, void* d_ws, size_t ws_size,
                              hipStream_t stream) {
    (void)in_sizes; (void)n_in; (void)out_size; (void)ws_size;
    const float* x_in    = (const float*)d_in[0];
    const int*   ei      = (const int*)d_in[1];
    const int*   batch   = (const int*)d_in[2];
    const float* pre_w1  = (const float*)d_in[3];
    const float* pre_b1  = (const float*)d_in[4];
    const float* pre_w2  = (const float*)d_in[5];
    const float* pre_b2  = (const float*)d_in[6];
    const float* conv_w  = (const float*)d_in[7];
    const float* conv_b  = (const float*)d_in[8];
    const float* ffnn_w1 = (const float*)d_in[9];
    const float* ffnn_b1 = (const float*)d_in[10];
    const float* ffnn_w2 = (const float*)d_in[11];
    const float* ffnn_b2 = (const float*)d_in[12];
    const float* bn_gamma= (const float*)d_in[13];
    const float* bn_beta = (const float*)d_in[14];
    const float* post_w1 = (const float*)d_in[15];
    const float* post_b1 = (const float*)d_in[16];
    const float* post_w2 = (const float*)d_in[17];
    const float* post_b2 = (const float*)d_in[18];
    const int* srcE = ei;
    const int* dstE = ei + EE;

    char* base = (char*)d_ws;
    size_t off = 0;
    auto carve = [&](size_t bytes) {
        char* q = base + off;
        off = (off + bytes + 255) & ~(size_t)255;
        return q;
    };
    float* xf32 = (float*)carve((size_t)NN * 128 * 4);
    unsigned short* zbf = (unsigned short*)carve((size_t)NN * 128 * 2);
    unsigned short* hbf = (unsigned short*)carve((size_t)NN * 128 * 2); // xw scratch
    float* dis   = (float*)carve((size_t)NN * 4);
    // zero-region: degi, fillc, pooled, cnt, bnstat contiguous -> ONE memset
    int*   degi  = (int*)carve((size_t)NN * 4);
    int*   fillc = (int*)carve((size_t)NN * 4);
    float* pooled= (float*)carve((size_t)GG * 128 * 4);
    int*   cnt   = (int*)carve((size_t)GG * 4);
    float* bnstat= (float*)carve(512 * 4); // [hop][sum|sq][128]
    size_t zlen  = (size_t)((char*)(bnstat + 512) - (char*)degi);
    int* incl    = (int*)carve((size_t)NN * 4);
    int* bsum    = (int*)carve(64 * 4);
    int* rowstart= (int*)carve((size_t)(NN + 1) * 4);
    int* colx    = (int*)carve((size_t)EE * 4);
    float* wn    = (float*)carve((size_t)EE * 4);
    unsigned short* Wt = (unsigned short*)carve((size_t)8 * 16384 * 2);

    hipMemsetAsync(degi, 0, zlen, stream);

    const int nsb = (NN + 1023) / 1024;
    k_deg<<<(EE + 255) / 256, 256, 0, stream>>>(dstE, degi, EE);
    k_scan1<<<nsb, 1024, 0, stream>>>(degi, incl, bsum, NN);
    k_scan3<<<(NN + 255) / 256, 256, 0, stream>>>(incl, degi, bsum, dis, rowstart, NN, EE, nsb);
    k_fill<<<(EE + 255) / 256, 256, 0, stream>>>(srcE, dstE, dis, rowstart, fillc, colx, wn, EE);
    k_prepw8<<<512, 256, 0, stream>>>(pre_w1, pre_w2, conv_w, conv_w + 16384,
                                      ffnn_w1, ffnn_w1 + 16384, ffnn_w2, ffnn_w2 + 16384, Wt);

    const int gB = (NN + 63) / 64;
    const float invN = 1.0f / NN;
    // preprocess FFNN + conv0
    k_mm<<<gB, 256, 0, stream>>>(x_in, nullptr, Wt + 0 * 16384, pre_b1, Wt + 1 * 16384, pre_b2,
                                 Wt + 2 * 16384, nullptr, nullptr, nullptr, nullptr,
                                 invN, 0, 0, xf32, hbf, NN);
    // hop 0
    k_agg<<<2048, 256, 0, stream>>>(hbf, rowstart, colx, wn, dis, conv_b,
                                    xf32, zbf, bnstat, bnstat + 128, NN);
    k_mm<<<gB, 256, 0, stream>>>(nullptr, zbf, Wt + 4 * 16384, ffnn_b1, Wt + 6 * 16384, ffnn_b2,
                                 Wt + 3 * 16384, bnstat, bnstat + 128, bn_gamma, bn_beta,
                                 invN, 1, 1, xf32, hbf, NN);
    // hop 1
    k_agg<<<2048, 256, 0, stream>>>(hbf, rowstart, colx, wn, dis, conv_b + 128,
                                    xf32, zbf, bnstat + 256, bnstat + 384, NN);
    k_mm<<<gB, 256, 0, stream>>>(nullptr, zbf, Wt + 5 * 16384, ffnn_b1 + 128, Wt + 7 * 16384, ffnn_b2 + 128,
                                 nullptr, bnstat + 256, bnstat + 384, bn_gamma + 128, bn_beta + 128,
                                 invN, 1, 1, xf32, nullptr, NN);
    // pool + post
    k_pool<<<1024, 128, 0, stream>>>(xf32, batch, pooled, cnt, NN);
    k_post<<<GG, 128, 0, stream>>>(pooled, cnt, post_w1, post_b1, post_w2, post_b2,
                                   (float*)d_out, GG);
}

// Round 8
// 374.738 us; speedup vs baseline: 1.8531x; 1.0582x over previous
//
#include <hip/hip_runtime.h>
#include <hip/hip_bf16.h>
#include <math.h>

#define NN 50000
#define EE 800000
#define GG 256

typedef short bf16x8 __attribute__((ext_vector_type(8)));
typedef float f32x4 __attribute__((ext_vector_type(4)));
typedef unsigned int u32x4 __attribute__((ext_vector_type(4)));

__device__ __forceinline__ unsigned short f2bf(float x) {
    __hip_bfloat16 h = __float2bfloat16(x);
    union { __hip_bfloat16 h; unsigned short u; } c; c.h = h; return c.u;
}
__device__ __forceinline__ float bf2f(unsigned short u) {
    union { unsigned int v; float f; } t; t.v = ((unsigned int)u) << 16; return t.f;
}
__device__ __forceinline__ float gelu_f(float v) {
    return 0.5f * v * (1.0f + erff(v * 0.70710678118654752f));
}
// XOR swizzle for [rows][128 bf16] LDS tiles (256B row stride)
__device__ __forceinline__ int swz(int row, int bytecol) {
    return row * 256 + (bytecol ^ ((row & 7) << 4));
}

// ---------------- graph prep ----------------
__global__ void k_deg(const int* __restrict__ dst, int* __restrict__ degi, int E) {
    int i = blockIdx.x * blockDim.x + threadIdx.x;
    if (i < E) atomicAdd(&degi[dst[i]], 1);
}
__global__ void k_scan1(const int* __restrict__ degi, int* __restrict__ incl,
                        int* __restrict__ bsum, int N) {
    __shared__ int sm[1024];
    int t = threadIdx.x, i = blockIdx.x * 1024 + t;
    int v = (i < N) ? degi[i] : 0;
    sm[t] = v;
    __syncthreads();
    for (int off = 1; off < 1024; off <<= 1) {
        int add = (t >= off) ? sm[t - off] : 0;
        __syncthreads();
        sm[t] += add;
        __syncthreads();
    }
    if (i < N) incl[i] = sm[t];
    if (t == 1023) bsum[blockIdx.x] = sm[t];
}
// rowstart = exclusive scan (block offset via wave-reduce over bsum) ; + dis
__global__ void k_scan3(const int* __restrict__ incl, const int* __restrict__ degi,
                        const int* __restrict__ bsum, float* __restrict__ dis,
                        int* __restrict__ rowstart, int N, int E, int nsb) {
    __shared__ int sboff;
    int t = threadIdx.x;
    if (t < 64) {
        int nb = blockIdx.x >> 2;
        int v = (t < nb && t < nsb) ? bsum[t] : 0;
        #pragma unroll
        for (int o = 1; o < 64; o <<= 1) v += __shfl_xor(v, o, 64);
        if (t == 0) sboff = v;
    }
    __syncthreads();
    int i = blockIdx.x * 256 + t;
    if (i < N) {
        rowstart[i] = incl[i] - degi[i] + sboff;
        dis[i] = rsqrtf((float)(degi[i] + 1)); // +1 self loop
    }
    if (i == 0) rowstart[N] = E;
}
__global__ void k_fill(const int* __restrict__ src, const int* __restrict__ dst,
                       const float* __restrict__ dis, const int* __restrict__ rowstart,
                       int* __restrict__ fillc, int* __restrict__ col,
                       float* __restrict__ wn, int E) {
    int i = blockIdx.x * blockDim.x + threadIdx.x;
    if (i < E) {
        int s = src[i], d = dst[i];
        int pos = rowstart[d] + atomicAdd(&fillc[d], 1);
        col[pos] = s;
        wn[pos] = dis[s] * dis[d];
    }
}
// all 8 weight matrices fp32 [k][n] -> bf16 transposed+preswizzled, one launch
__global__ void k_prepw8(const float* __restrict__ w0, const float* __restrict__ w1,
                         const float* __restrict__ w2, const float* __restrict__ w3,
                         const float* __restrict__ w4, const float* __restrict__ w5,
                         const float* __restrict__ w6, const float* __restrict__ w7,
                         unsigned short* __restrict__ Wt) {
    int b = blockIdx.x >> 6;
    const float* W = b == 0 ? w0 : b == 1 ? w1 : b == 2 ? w2 : b == 3 ? w3
                   : b == 4 ? w4 : b == 5 ? w5 : b == 6 ? w6 : w7;
    int tid = (blockIdx.x & 63) * 256 + threadIdx.x;
    int n = tid >> 7, k = tid & 127;
    *(unsigned short*)((char*)(Wt + (size_t)b * 16384) + swz(n, k * 2)) = f2bf(W[k * 128 + n]);
}

// ---------------- fused 3-matmul chain ----------------
// x' = [BN](A); h = gelu(x'@W1+b1); y = h@W2+b2 [+ x' residual from regs] -> outx32;
// optional stage3: out3 = bf16(y)@W3  (conv for next hop).
__global__ __launch_bounds__(256) void k_mm(
    const float* __restrict__ A32, const unsigned short* __restrict__ A16,
    const unsigned short* __restrict__ W1, const float* __restrict__ b1,
    const unsigned short* __restrict__ W2, const float* __restrict__ b2,
    const unsigned short* __restrict__ W3,
    const float* __restrict__ st_sum, const float* __restrict__ st_sq,
    const float* __restrict__ st_g, const float* __restrict__ st_b,
    float invN, int bn, int hasres,
    float* __restrict__ outx32, unsigned short* __restrict__ out3, int M)
{
    __shared__ unsigned short As[64 * 128];
    __shared__ unsigned short Ws[128 * 128];
    __shared__ float lsc[128], lsh[128];
    const int tid = threadIdx.x;
    const int bm = blockIdx.x * 64;
    if (st_sum && tid < 128) {
        float m = st_sum[tid] * invN;
        float var = st_sq[tid] * invN - m * m;
        float s = st_g[tid] * rsqrtf(var + 1e-5f);
        lsc[tid] = s;
        lsh[tid] = st_b[tid] - m * s;
    }
    __syncthreads();
    { // stage W1
        const uint4* srcp = (const uint4*)W1;
        uint4* dstp = (uint4*)Ws;
        for (int i = tid; i < 2048; i += 256) dstp[i] = srcp[i];
    }
    // stage A, 4 passes of 16 rows; optional BN affine
    #pragma unroll
    for (int pass = 0; pass < 4; ++pass) {
        int row = pass * 16 + (tid >> 4);
        int c8 = tid & 15;
        int gr = bm + row; if (gr > M - 1) gr = M - 1;
        float vv[8];
        if (A32) {
            const float* pp = A32 + (size_t)gr * 128 + c8 * 8;
            float4 v0 = *(const float4*)pp;
            float4 v1 = *(const float4*)(pp + 4);
            vv[0] = v0.x; vv[1] = v0.y; vv[2] = v0.z; vv[3] = v0.w;
            vv[4] = v1.x; vv[5] = v1.y; vv[6] = v1.z; vv[7] = v1.w;
        } else {
            u32x4 raw = __builtin_nontemporal_load((const u32x4*)(A16 + (size_t)gr * 128 + c8 * 8));
            #pragma unroll
            for (int d = 0; d < 4; ++d) {
                vv[2 * d]     = bf2f((unsigned short)(raw[d] & 0xffff));
                vv[2 * d + 1] = bf2f((unsigned short)(raw[d] >> 16));
            }
        }
        if (bn) {
            int ch = c8 * 8;
            #pragma unroll
            for (int j = 0; j < 8; ++j) vv[j] = vv[j] * lsc[ch + j] + lsh[ch + j];
        }
        unsigned short tmp[8];
        #pragma unroll
        for (int j = 0; j < 8; ++j) tmp[j] = f2bf(vv[j]);
        *(uint4*)((char*)As + swz(row, c8 * 16)) = *(uint4*)tmp;
    }
    __syncthreads();

    const int lane = tid & 63, wid = tid >> 6;
    const int r0 = wid * 16;
    const int lrow = lane & 15;
    const int lkb = (lane >> 4) * 16;
    const int cb = lane & 15;
    const int rb = r0 + (lane >> 4) * 4;

    f32x4 acc[8];
    // ---- mm1 ----
    #pragma unroll
    for (int n = 0; n < 8; ++n) acc[n] = (f32x4){0.f, 0.f, 0.f, 0.f};
    #pragma unroll
    for (int kk = 0; kk < 4; ++kk) {
        int bc = kk * 64 + lkb;
        bf16x8 a = *(const bf16x8*)((const char*)As + swz(r0 + lrow, bc));
        #pragma unroll
        for (int n = 0; n < 8; ++n) {
            bf16x8 b = *(const bf16x8*)((const char*)Ws + swz(n * 16 + lrow, bc));
            acc[n] = __builtin_amdgcn_mfma_f32_16x16x32_bf16(a, b, acc[n], 0, 0, 0);
        }
    }
    // capture residual x' (BN'd A) from own epilogue slots BEFORE epi1 overwrites
    unsigned short rres[32];
    if (hasres) {
        #pragma unroll
        for (int n = 0; n < 8; ++n)
            #pragma unroll
            for (int j = 0; j < 4; ++j)
                rres[n * 4 + j] = *(const unsigned short*)((const char*)As + swz(rb + j, (n * 16 + cb) * 2));
    }
    // epi1: gelu -> h into own As slab (rows rb..rb+3 are wave-private)
    #pragma unroll
    for (int n = 0; n < 8; ++n) {
        int colg = n * 16 + cb;
        float bv = b1[colg];
        #pragma unroll
        for (int j = 0; j < 4; ++j) {
            float v = gelu_f(acc[n][j] + bv);
            *(unsigned short*)((char*)As + swz(rb + j, colg * 2)) = f2bf(v);
        }
    }
    __syncthreads(); // all waves done reading W1
    { // stage W2
        const uint4* srcp = (const uint4*)W2;
        uint4* dstp = (uint4*)Ws;
        for (int i = tid; i < 2048; i += 256) dstp[i] = srcp[i];
    }
    __syncthreads();
    // ---- mm2 ----
    #pragma unroll
    for (int n = 0; n < 8; ++n) acc[n] = (f32x4){0.f, 0.f, 0.f, 0.f};
    #pragma unroll
    for (int kk = 0; kk < 4; ++kk) {
        int bc = kk * 64 + lkb;
        bf16x8 a = *(const bf16x8*)((const char*)As + swz(r0 + lrow, bc));
        #pragma unroll
        for (int n = 0; n < 8; ++n) {
            bf16x8 b = *(const bf16x8*)((const char*)Ws + swz(n * 16 + lrow, bc));
            acc[n] = __builtin_amdgcn_mfma_f32_16x16x32_bf16(a, b, acc[n], 0, 0, 0);
        }
    }
    // epi2: + b2 (+ register residual) -> outx32; bf16 copy into As for stage3
    #pragma unroll
    for (int n = 0; n < 8; ++n) {
        int colg = n * 16 + cb;
        float bv = b2[colg];
        #pragma unroll
        for (int j = 0; j < 4; ++j) {
            int rowg = bm + rb + j;
            float v = acc[n][j] + bv;
            if (hasres) v += bf2f(rres[n * 4 + j]);
            if (rowg < M) outx32[(size_t)rowg * 128 + colg] = v;
            if (W3) *(unsigned short*)((char*)As + swz(rb + j, colg * 2)) = f2bf(v);
        }
    }
    if (!W3) return;
    __syncthreads(); // all waves done reading W2
    { // stage W3
        const uint4* srcp = (const uint4*)W3;
        uint4* dstp = (uint4*)Ws;
        for (int i = tid; i < 2048; i += 256) dstp[i] = srcp[i];
    }
    __syncthreads();
    // ---- mm3 (conv) ----
    #pragma unroll
    for (int n = 0; n < 8; ++n) acc[n] = (f32x4){0.f, 0.f, 0.f, 0.f};
    #pragma unroll
    for (int kk = 0; kk < 4; ++kk) {
        int bc = kk * 64 + lkb;
        bf16x8 a = *(const bf16x8*)((const char*)As + swz(r0 + lrow, bc));
        #pragma unroll
        for (int n = 0; n < 8; ++n) {
            bf16x8 b = *(const bf16x8*)((const char*)Ws + swz(n * 16 + lrow, bc));
            acc[n] = __builtin_amdgcn_mfma_f32_16x16x32_bf16(a, b, acc[n], 0, 0, 0);
        }
    }
    #pragma unroll
    for (int n = 0; n < 8; ++n) {
        int colg = n * 16 + cb;
        #pragma unroll
        for (int j = 0; j < 4; ++j) {
            int rowg = bm + rb + j;
            if (rowg < M) out3[(size_t)rowg * 128 + colg] = f2bf(acc[n][j]);
        }
    }
}

// ---------------- CSR aggregation + residual + BN partial stats ----------------
// 4-wide gather loop (16 edges in flight per wave-iteration) to amortize the
// col->row dependent-load chain. col/wn cached normally; x0/z non-temporal.
__global__ __launch_bounds__(256) void k_agg(
    const unsigned short* __restrict__ xw, const int* __restrict__ rowstart,
    const int* __restrict__ col, const float* __restrict__ wn,
    const float* __restrict__ dis, const float* __restrict__ convb,
    const float* __restrict__ x0, unsigned short* __restrict__ zbf,
    float* __restrict__ bnsum, float* __restrict__ bnsq, int N)
{
    __shared__ float redS[4][128];
    __shared__ float redQ[4][128];
    const int tid = threadIdx.x;
    const int lane = tid & 63;
    const int wid = tid >> 6;
    const int g = lane >> 4;
    const int cl = lane & 15;
    const int ch = cl * 8;
    const int wave = blockIdx.x * 4 + wid;
    const int nwaves = gridDim.x * 4;

    float cb[8];
    #pragma unroll
    for (int j = 0; j < 8; ++j) cb[j] = convb[ch + j];
    float s[8], q[8];
    #pragma unroll
    for (int j = 0; j < 8; ++j) { s[j] = 0.f; q[j] = 0.f; }

    for (int v = wave; v < N; v += nwaves) {
        const int e0 = rowstart[v], e1 = rowstart[v + 1];
        float a[8];
        #pragma unroll
        for (int j = 0; j < 8; ++j) a[j] = 0.f;
        int e = e0 + g;
        // 4-wide: 4 independent gathers in flight per iteration (16 edges/wave)
        for (; e + 12 < e1; e += 16) {
            const int u0 = col[e];
            const int u1 = col[e + 4];
            const int u2 = col[e + 8];
            const int u3 = col[e + 12];
            const float w0 = wn[e];
            const float w1 = wn[e + 4];
            const float w2 = wn[e + 8];
            const float w3 = wn[e + 12];
            u32x4 p0 = *(const u32x4*)(xw + (size_t)u0 * 128 + ch);
            u32x4 p1 = *(const u32x4*)(xw + (size_t)u1 * 128 + ch);
            u32x4 p2 = *(const u32x4*)(xw + (size_t)u2 * 128 + ch);
            u32x4 p3 = *(const u32x4*)(xw + (size_t)u3 * 128 + ch);
            #pragma unroll
            for (int d = 0; d < 4; ++d) {
                a[2 * d]     += w0 * bf2f((unsigned short)(p0[d] & 0xffff));
                a[2 * d + 1] += w0 * bf2f((unsigned short)(p0[d] >> 16));
            }
            #pragma unroll
            for (int d = 0; d < 4; ++d) {
                a[2 * d]     += w1 * bf2f((unsigned short)(p1[d] & 0xffff));
                a[2 * d + 1] += w1 * bf2f((unsigned short)(p1[d] >> 16));
            }
            #pragma unroll
            for (int d = 0; d < 4; ++d) {
                a[2 * d]     += w2 * bf2f((unsigned short)(p2[d] & 0xffff));
                a[2 * d + 1] += w2 * bf2f((unsigned short)(p2[d] >> 16));
            }
            #pragma unroll
            for (int d = 0; d < 4; ++d) {
                a[2 * d]     += w3 * bf2f((unsigned short)(p3[d] & 0xffff));
                a[2 * d + 1] += w3 * bf2f((unsigned short)(p3[d] >> 16));
            }
        }
        for (; e + 4 < e1; e += 8) {
            const int u0 = col[e];
            const int u1 = col[e + 4];
            const float w0 = wn[e];
            const float w1 = wn[e + 4];
            u32x4 p0 = *(const u32x4*)(xw + (size_t)u0 * 128 + ch);
            u32x4 p1 = *(const u32x4*)(xw + (size_t)u1 * 128 + ch);
            #pragma unroll
            for (int d = 0; d < 4; ++d) {
                a[2 * d]     += w0 * bf2f((unsigned short)(p0[d] & 0xffff));
                a[2 * d + 1] += w0 * bf2f((unsigned short)(p0[d] >> 16));
            }
            #pragma unroll
            for (int d = 0; d < 4; ++d) {
                a[2 * d]     += w1 * bf2f((unsigned short)(p1[d] & 0xffff));
                a[2 * d + 1] += w1 * bf2f((unsigned short)(p1[d] >> 16));
            }
        }
        if (e < e1) {
            const int u = col[e];
            const float w = wn[e];
            u32x4 p = *(const u32x4*)(xw + (size_t)u * 128 + ch);
            #pragma unroll
            for (int d = 0; d < 4; ++d) {
                a[2 * d]     += w * bf2f((unsigned short)(p[d] & 0xffff));
                a[2 * d + 1] += w * bf2f((unsigned short)(p[d] >> 16));
            }
        }
        #pragma unroll
        for (int j = 0; j < 8; ++j) {
            a[j] += __shfl_xor(a[j], 16, 64);
            a[j] += __shfl_xor(a[j], 32, 64);
        }
        if (g == 0) {
            const float dv = dis[v];
            const float sw = dv * dv;
            u32x4 p = *(const u32x4*)(xw + (size_t)v * 128 + ch);
            f32x4 xa = __builtin_nontemporal_load((const f32x4*)(x0 + (size_t)v * 128 + ch));
            f32x4 xb = __builtin_nontemporal_load((const f32x4*)(x0 + (size_t)v * 128 + ch + 4));
            const float xr[8] = { xa[0], xa[1], xa[2], xa[3], xb[0], xb[1], xb[2], xb[3] };
            float zz[8];
            #pragma unroll
            for (int d = 0; d < 4; ++d) {
                zz[2 * d]     = a[2 * d]     + sw * bf2f((unsigned short)(p[d] & 0xffff));
                zz[2 * d + 1] = a[2 * d + 1] + sw * bf2f((unsigned short)(p[d] >> 16));
            }
            unsigned short zo[8];
            #pragma unroll
            for (int j = 0; j < 8; ++j) {
                zz[j] += cb[j] + xr[j];
                s[j] += zz[j];
                q[j] += zz[j] * zz[j];
                zo[j] = f2bf(zz[j]);
            }
            __builtin_nontemporal_store(*(const u32x4*)zo, (u32x4*)(zbf + (size_t)v * 128 + ch));
        }
    }
    if (g == 0) {
        #pragma unroll
        for (int j = 0; j < 8; ++j) { redS[wid][ch + j] = s[j]; redQ[wid][ch + j] = q[j]; }
    }
    __syncthreads();
    if (tid < 128) {
        float ts = redS[0][tid] + redS[1][tid] + redS[2][tid] + redS[3][tid];
        float tq = redQ[0][tid] + redQ[1][tid] + redQ[2][tid] + redQ[3][tid];
        atomicAdd(&bnsum[tid], ts);
        atomicAdd(&bnsq[tid], tq);
    }
}
// node-partitioned pooling: per-block partial sums flushed via atomics
__global__ __launch_bounds__(128) void k_pool(
    const float* __restrict__ x, const int* __restrict__ batch,
    float* __restrict__ pooled, int* __restrict__ cnt, int N)
{
    const int t = threadIdx.x;
    const int per = (N + gridDim.x - 1) / gridDim.x;
    const int s = blockIdx.x * per;
    const int e = min(s + per, N);
    if (s >= e) return;
    float acc = 0.f;
    int gcur = batch[s];
    int run = 0;
    for (int v = s; v < e; ++v) {
        int g = batch[v];
        if (g != gcur) {
            atomicAdd(&pooled[(size_t)gcur * 128 + t], acc);
            if (t == 0) atomicAdd(&cnt[gcur], run);
            acc = 0.f; run = 0; gcur = g;
        }
        acc += __builtin_nontemporal_load(x + (size_t)v * 128 + t);
        ++run;
    }
    atomicAdd(&pooled[(size_t)gcur * 128 + t], acc);
    if (t == 0) atomicAdd(&cnt[gcur], run);
}
// post FFNN (exact fp32)
__global__ __launch_bounds__(128) void k_post(
    const float* __restrict__ pooled, const int* __restrict__ cnt,
    const float* __restrict__ w1, const float* __restrict__ b1,
    const float* __restrict__ w2, const float* __restrict__ b2,
    float* __restrict__ out, int G)
{
    __shared__ float pr[128], hr[128];
    int g = blockIdx.x, t = threadIdx.x;
    float c = fmaxf((float)cnt[g], 1.0f);
    pr[t] = pooled[(size_t)g * 128 + t] / c;
    __syncthreads();
    float a = b1[t];
    for (int k = 0; k < 128; ++k) a += pr[k] * w1[k * 128 + t];
    hr[t] = gelu_f(a);
    __syncthreads();
    if (t < 64) {
        float o = b2[t];
        for (int k = 0; k < 128; ++k) o += hr[k] * w2[k * 64 + t];
        out[g * 64 + t] = o;
    }
}

extern "C" void kernel_launch(void* const* d_in, const int* in_sizes, int n_in,
                              void* d_out, int out_size, void* d_ws, size_t ws_size,
                              hipStream_t stream) {
    (void)in_sizes; (void)n_in; (void)out_size; (void)ws_size;
    const float* x_in    = (const float*)d_in[0];
    const int*   ei      = (const int*)d_in[1];
    const int*   batch   = (const int*)d_in[2];
    const float* pre_w1  = (const float*)d_in[3];
    const float* pre_b1  = (const float*)d_in[4];
    const float* pre_w2  = (const float*)d_in[5];
    const float* pre_b2  = (const float*)d_in[6];
    const float* conv_w  = (const float*)d_in[7];
    const float* conv_b  = (const float*)d_in[8];
    const float* ffnn_w1 = (const float*)d_in[9];
    const float* ffnn_b1 = (const float*)d_in[10];
    const float* ffnn_w2 = (const float*)d_in[11];
    const float* ffnn_b2 = (const float*)d_in[12];
    const float* bn_gamma= (const float*)d_in[13];
    const float* bn_beta = (const float*)d_in[14];
    const float* post_w1 = (const float*)d_in[15];
    const float* post_b1 = (const float*)d_in[16];
    const float* post_w2 = (const float*)d_in[17];
    const float* post_b2 = (const float*)d_in[18];
    const int* srcE = ei;
    const int* dstE = ei + EE;

    char* base = (char*)d_ws;
    size_t off = 0;
    auto carve = [&](size_t bytes) {
        char* q = base + off;
        off = (off + bytes + 255) & ~(size_t)255;
        return q;
    };
    float* xf32 = (float*)carve((size_t)NN * 128 * 4);
    unsigned short* zbf = (unsigned short*)carve((size_t)NN * 128 * 2);
    unsigned short* hbf = (unsigned short*)carve((size_t)NN * 128 * 2); // xw scratch
    float* dis   = (float*)carve((size_t)NN * 4);
    // zero-region: degi, fillc, pooled, cnt, bnstat contiguous -> ONE memset
    int*   degi  = (int*)carve((size_t)NN * 4);
    int*   fillc = (int*)carve((size_t)NN * 4);
    float* pooled= (float*)carve((size_t)GG * 128 * 4);
    int*   cnt   = (int*)carve((size_t)GG * 4);
    float* bnstat= (float*)carve(512 * 4); // [hop][sum|sq][128]
    size_t zlen  = (size_t)((char*)(bnstat + 512) - (char*)degi);
    int* incl    = (int*)carve((size_t)NN * 4);
    int* bsum    = (int*)carve(64 * 4);
    int* rowstart= (int*)carve((size_t)(NN + 1) * 4);
    int* colx    = (int*)carve((size_t)EE * 4);
    float* wn    = (float*)carve((size_t)EE * 4);
    unsigned short* Wt = (unsigned short*)carve((size_t)8 * 16384 * 2);

    hipMemsetAsync(degi, 0, zlen, stream);

    const int nsb = (NN + 1023) / 1024;
    k_deg<<<(EE + 255) / 256, 256, 0, stream>>>(dstE, degi, EE);
    k_scan1<<<nsb, 1024, 0, stream>>>(degi, incl, bsum, NN);
    k_scan3<<<(NN + 255) / 256, 256, 0, stream>>>(incl, degi, bsum, dis, rowstart, NN, EE, nsb);
    k_fill<<<(EE + 255) / 256, 256, 0, stream>>>(srcE, dstE, dis, rowstart, fillc, colx, wn, EE);
    k_prepw8<<<512, 256, 0, stream>>>(pre_w1, pre_w2, conv_w, conv_w + 16384,
                                      ffnn_w1, ffnn_w1 + 16384, ffnn_w2, ffnn_w2 + 16384, Wt);

    const int gB = (NN + 63) / 64;
    const float invN = 1.0f / NN;
    // preprocess FFNN + conv0
    k_mm<<<gB, 256, 0, stream>>>(x_in, nullptr, Wt + 0 * 16384, pre_b1, Wt + 1 * 16384, pre_b2,
                                 Wt + 2 * 16384, nullptr, nullptr, nullptr, nullptr,
                                 invN, 0, 0, xf32, hbf, NN);
    // hop 0
    k_agg<<<2048, 256, 0, stream>>>(hbf, rowstart, colx, wn, dis, conv_b,
                                    xf32, zbf, bnstat, bnstat + 128, NN);
    k_mm<<<gB, 256, 0, stream>>>(nullptr, zbf, Wt + 4 * 16384, ffnn_b1, Wt + 6 * 16384, ffnn_b2,
                                 Wt + 3 * 16384, bnstat, bnstat + 128, bn_gamma, bn_beta,
                                 invN, 1, 1, xf32, hbf, NN);
    // hop 1
    k_agg<<<2048, 256, 0, stream>>>(hbf, rowstart, colx, wn, dis, conv_b + 128,
                                    xf32, zbf, bnstat + 256, bnstat + 384, NN);
    k_mm<<<gB, 256, 0, stream>>>(nullptr, zbf, Wt + 5 * 16384, ffnn_b1 + 128, Wt + 7 * 16384, ffnn_b2 + 128,
                                 nullptr, bnstat + 256, bnstat + 384, bn_gamma + 128, bn_beta + 128,
                                 invN, 1, 1, xf32, nullptr, NN);
    // pool + post
    k_pool<<<1024, 128, 0, stream>>>(xf32, batch, pooled, cnt, NN);
    k_post<<<GG, 128, 0, stream>>>(pooled, cnt, post_w1, post_b1, post_w2, post_b2,
                                   (float*)d_out, GG);
}